// Round 1
// baseline (2273.217 us; speedup 1.0000x reference)
//
#include <hip/hip_runtime.h>

#define SEQ 2048
#define DM 256
#define NH 8
#define DKH 32
#define NBATCH 4
#define SCALE 0.17677669529663687f

// ---------------------------------------------------------------- LayerNorm
// one wave per row (D=256 -> 4 floats/lane), 4 rows per 256-block
__global__ __launch_bounds__(256) void ln_kernel(const float* __restrict__ X,
    const float* __restrict__ G, const float* __restrict__ Bv, float* __restrict__ Y){
  int row = blockIdx.x*4 + (threadIdx.x>>6);
  int lane = threadIdx.x & 63;
  const float4 v = *(const float4*)(X + (size_t)row*DM + lane*4);
  float s = v.x+v.y+v.z+v.w;
  #pragma unroll
  for (int off=32; off; off>>=1) s += __shfl_xor(s, off, 64);
  float mean = s * (1.0f/DM);
  float dx=v.x-mean, dy=v.y-mean, dz=v.z-mean, dw=v.w-mean;
  float ss = dx*dx+dy*dy+dz*dz+dw*dw;
  #pragma unroll
  for (int off=32; off; off>>=1) ss += __shfl_xor(ss, off, 64);
  float r = rsqrtf(ss*(1.0f/DM) + 1e-6f);
  const float4 g = *(const float4*)(G + lane*4);
  const float4 b = *(const float4*)(Bv + lane*4);
  float4 o;
  o.x = dx*r*g.x + b.x;
  o.y = dy*r*g.y + b.y;
  o.z = dz*r*g.z + b.z;
  o.w = dw*r*g.w + b.w;
  *(float4*)(Y + (size_t)row*DM + lane*4) = o;
}

// ---------------------------------------------------------------- fp32 GEMM
// C[M,N] = A[M,K]*B[K,N] + bias (+Res) (+relu). 64x64 tile, 256 thr, 4x4/thr.
__global__ __launch_bounds__(256) void gemm_kernel(const float* __restrict__ A,
    const float* __restrict__ Bm, const float* __restrict__ bias,
    const float* __restrict__ Res, float* __restrict__ C,
    int M, int N, int K, int relu){
  __shared__ float sA[16][68];
  __shared__ float sB[16][68];
  int nbk = N >> 6;
  int bx = blockIdx.x % nbk;
  int by = blockIdx.x / nbk;
  int m0 = by << 6, n0 = bx << 6;
  int tx = threadIdx.x & 15, ty = threadIdx.x >> 4;
  int alr = threadIdx.x >> 2;            // 0..63 A row in tile
  int alc = (threadIdx.x & 3) << 2;      // 0,4,8,12 A k-col
  int blr = threadIdx.x >> 4;            // 0..15 B k-row
  int blc = (threadIdx.x & 15) << 2;     // 0..60 B n-col
  float acc[4][4] = {{0.f}};
  for (int k0=0; k0<K; k0+=16){
    float4 a  = *(const float4*)&A [(size_t)(m0+alr)*K + k0 + alc];
    float4 bq = *(const float4*)&Bm[(size_t)(k0+blr)*N + n0 + blc];
    __syncthreads();
    sA[alc+0][alr]=a.x; sA[alc+1][alr]=a.y; sA[alc+2][alr]=a.z; sA[alc+3][alr]=a.w;
    *(float4*)&sB[blr][blc] = bq;
    __syncthreads();
    #pragma unroll
    for (int kk=0;kk<16;++kk){
      float4 av = *(const float4*)&sA[kk][ty<<2];
      float4 bv = *(const float4*)&sB[kk][tx<<2];
      acc[0][0]+=av.x*bv.x; acc[0][1]+=av.x*bv.y; acc[0][2]+=av.x*bv.z; acc[0][3]+=av.x*bv.w;
      acc[1][0]+=av.y*bv.x; acc[1][1]+=av.y*bv.y; acc[1][2]+=av.y*bv.z; acc[1][3]+=av.y*bv.w;
      acc[2][0]+=av.z*bv.x; acc[2][1]+=av.z*bv.y; acc[2][2]+=av.z*bv.z; acc[2][3]+=av.z*bv.w;
      acc[3][0]+=av.w*bv.x; acc[3][1]+=av.w*bv.y; acc[3][2]+=av.w*bv.z; acc[3][3]+=av.w*bv.w;
    }
  }
  float4 bb;
  if (bias) bb = *(const float4*)&bias[n0+(tx<<2)];
  else { bb.x=0.f; bb.y=0.f; bb.z=0.f; bb.w=0.f; }
  #pragma unroll
  for (int i=0;i<4;++i){
    size_t row = (size_t)m0 + (ty<<2) + i;
    float4 o;
    o.x=acc[i][0]+bb.x; o.y=acc[i][1]+bb.y; o.z=acc[i][2]+bb.z; o.w=acc[i][3]+bb.w;
    if (Res){
      float4 rr = *(const float4*)&Res[row*N + n0+(tx<<2)];
      o.x+=rr.x; o.y+=rr.y; o.z+=rr.z; o.w+=rr.w;
    }
    if (relu){
      o.x=fmaxf(o.x,0.f); o.y=fmaxf(o.y,0.f); o.z=fmaxf(o.z,0.f); o.w=fmaxf(o.w,0.f);
    }
    *(float4*)&C[row*N + n0+(tx<<2)] = o;
  }
}

// ------------------------------------------------- attention pass 1: m, l
// grid = B*H*8(qc)*4(kc), block 256 (1 q-row per thread, 512-key chunk)
__global__ __launch_bounds__(256) void attn_stats_kernel(const float* __restrict__ Q,
    const float* __restrict__ Kx, float* __restrict__ Ms, float* __restrict__ Ls){
  __shared__ float sK[64*DKH];
  int blk = blockIdx.x;
  int kc = blk & 3;
  int qc = (blk >> 2) & 7;
  int bh = blk >> 5;                      // 0..31
  int h = bh & 7, b = bh >> 3;
  int qi = (qc << 8) + threadIdx.x;
  const float* qp = Q + ((size_t)(b*SEQ + qi))*DM + h*DKH;
  float4 qv[8];
  #pragma unroll
  for (int j=0;j<8;++j) qv[j] = *(const float4*)(qp + j*4);
  int lr = threadIdx.x >> 2;
  int lc = (threadIdx.x & 3) << 3;
  float m = -__builtin_inff(), l = 0.0f;
  int tbeg = kc << 9;
  for (int t0 = tbeg; t0 < tbeg + 512; t0 += 64){
    const float* kp = Kx + ((size_t)(b*SEQ + t0 + lr))*DM + h*DKH + lc;
    float4 k0 = *(const float4*)kp;
    float4 k1 = *(const float4*)(kp + 4);
    __syncthreads();
    *(float4*)&sK[lr*DKH + lc]     = k0;
    *(float4*)&sK[lr*DKH + lc + 4] = k1;
    __syncthreads();
    #pragma unroll 2
    for (int r=0;r<64;++r){
      const float4* kr = (const float4*)&sK[r*DKH];
      float s0=0.f,s1=0.f,s2=0.f,s3=0.f;
      #pragma unroll
      for (int jj=0;jj<8;++jj){
        float4 kk = kr[jj], qq = qv[jj];
        s0 += qq.x*kk.x; s1 += qq.y*kk.y; s2 += qq.z*kk.z; s3 += qq.w*kk.w;
      }
      float s = ((s0+s1)+(s2+s3)) * SCALE;
      float mn = fmaxf(m, s);
      l = l*__expf(m-mn) + __expf(s-mn);
      m = mn;
    }
  }
  size_t si = (((size_t)bh*SEQ + qi) << 2) + kc;
  Ms[si] = m; Ls[si] = l;
}

// --------------------------- attention pass 2: O partials + column sums
__global__ __launch_bounds__(256) void attn_pass2_kernel(const float* __restrict__ Q,
    const float* __restrict__ Kx, const float* __restrict__ Vx,
    const float* __restrict__ Ms, const float* __restrict__ Ls,
    float* __restrict__ opart, float* __restrict__ colPart){
  __shared__ float sK[64*DKH];
  __shared__ float sV[64*DKH];
  __shared__ float sCol[4][64];
  int blk = blockIdx.x;
  int kc = blk & 3;
  int qc = (blk >> 2) & 7;
  int bh = blk >> 5;
  int h = bh & 7, b = bh >> 3;
  int qi = (qc << 8) + threadIdx.x;
  const float* qp = Q + ((size_t)(b*SEQ + qi))*DM + h*DKH;
  float4 qv[8];
  #pragma unroll
  for (int j=0;j<8;++j) qv[j] = *(const float4*)(qp + j*4);
  // combine the 4 chunk stats -> global m, l for this row
  size_t sb = ((size_t)bh*SEQ + qi) << 2;
  float mA=Ms[sb], mB=Ms[sb+1], mC=Ms[sb+2], mD=Ms[sb+3];
  float Mv = fmaxf(fmaxf(mA,mB), fmaxf(mC,mD));
  float Lv = Ls[sb]  *__expf(mA-Mv) + Ls[sb+1]*__expf(mB-Mv)
           + Ls[sb+2]*__expf(mC-Mv) + Ls[sb+3]*__expf(mD-Mv);
  float invl = 1.0f / Lv;
  float4 ov[8];
  #pragma unroll
  for (int j=0;j<8;++j){ ov[j].x=0.f; ov[j].y=0.f; ov[j].z=0.f; ov[j].w=0.f; }
  int lr = threadIdx.x >> 2, lc = (threadIdx.x & 3) << 3;
  int wid = threadIdx.x >> 6;
  int lanei = threadIdx.x & 63;
  int tbeg = kc << 9;
  for (int t0 = tbeg; t0 < tbeg + 512; t0 += 64){
    const float* kp = Kx + ((size_t)(b*SEQ + t0 + lr))*DM + h*DKH + lc;
    const float* vp = Vx + ((size_t)(b*SEQ + t0 + lr))*DM + h*DKH + lc;
    float4 k0=*(const float4*)kp, k1=*(const float4*)(kp+4);
    float4 v0=*(const float4*)vp, v1=*(const float4*)(vp+4);
    __syncthreads();
    *(float4*)&sK[lr*DKH+lc]=k0; *(float4*)&sK[lr*DKH+lc+4]=k1;
    *(float4*)&sV[lr*DKH+lc]=v0; *(float4*)&sV[lr*DKH+lc+4]=v1;
    __syncthreads();
    #pragma unroll 2
    for (int r=0;r<64;++r){
      const float4* kr = (const float4*)&sK[r*DKH];
      float s0=0.f,s1=0.f,s2=0.f,s3=0.f;
      #pragma unroll
      for (int jj=0;jj<8;++jj){
        float4 kk = kr[jj], qq = qv[jj];
        s0 += qq.x*kk.x; s1 += qq.y*kk.y; s2 += qq.z*kk.z; s3 += qq.w*kk.w;
      }
      float s = ((s0+s1)+(s2+s3)) * SCALE;
      float w = __expf(s - Mv) * invl;      // final normalized weight
      const float4* vr = (const float4*)&sV[r*DKH];
      #pragma unroll
      for (int jj=0;jj<8;++jj){
        float4 vv = vr[jj];
        ov[jj].x += w*vv.x; ov[jj].y += w*vv.y; ov[jj].z += w*vv.z; ov[jj].w += w*vv.w;
      }
      float wsum = w;
      #pragma unroll
      for (int off=32; off; off>>=1) wsum += __shfl_xor(wsum, off, 64);
      if (lanei == 0) sCol[wid][r] = wsum;
    }
    __syncthreads();
    if (threadIdx.x < 64){
      float c = sCol[0][threadIdx.x]+sCol[1][threadIdx.x]
              + sCol[2][threadIdx.x]+sCol[3][threadIdx.x];
      colPart[((size_t)(bh*8+qc))*SEQ + t0 + threadIdx.x] = c;
    }
  }
  float* op = opart + (size_t)kc*2097152 + ((size_t)(b*SEQ+qi))*DM + h*DKH;
  #pragma unroll
  for (int jj=0;jj<8;++jj) *(float4*)(op + jj*4) = ov[jj];
}

// ---------------------------------------------------- reduce 4 O partials
__global__ __launch_bounds__(256) void oreduce_kernel(const float* __restrict__ opart,
                                                      float* __restrict__ O){
  size_t i = ((size_t)blockIdx.x*256 + threadIdx.x)*4;
  float4 a = *(const float4*)(opart + i);
  float4 b = *(const float4*)(opart + 2097152 + i);
  float4 c = *(const float4*)(opart + 4194304 + i);
  float4 d = *(const float4*)(opart + 6291456 + i);
  a.x += b.x+c.x+d.x; a.y += b.y+c.y+d.y; a.z += b.z+c.z+d.z; a.w += b.w+c.w+d.w;
  *(float4*)(O + i) = a;
}

// ------------------------------------- importance = 0.7*G + 0.3*L (fp64 acc)
__global__ __launch_bounds__(256) void imp_kernel(const float* __restrict__ colG,
    const float* __restrict__ colL, float* __restrict__ imp){
  int i = blockIdx.x*256 + threadIdx.x;   // b*2048 + t
  int b = i >> 11, t = i & 2047;
  double sg = 0.0, sl = 0.0;
  for (int h=0; h<8; ++h)
    for (int qc=0; qc<8; ++qc){
      size_t base = ((size_t)((b*8+h)*8+qc))*SEQ + t;
      sg += (double)colG[base];
      sl += (double)colL[base];
    }
  imp[i] = (float)(0.7*sg + 0.3*sl);
}

// ------------------------- top-K per batch (stable: value desc, index asc)
__global__ __launch_bounds__(1024) void topk_kernel(const float* __restrict__ imp,
    int KK, int* __restrict__ idxout){
  __shared__ float sv[2048];
  __shared__ int scnt[1024];
  int b = blockIdx.x;
  for (int i=threadIdx.x; i<2048; i+=1024) sv[i] = imp[b*2048 + i];
  __syncthreads();
  int i0 = threadIdx.x*2;
  float v0 = sv[i0], v1 = sv[i0+1];
  int r0 = 0, r1 = 0;
  for (int j=0; j<2048; ++j){
    float vj = sv[j];
    r0 += (vj > v0) || (vj == v0 && j < i0);
    r1 += (vj > v1) || (vj == v1 && j < i0+1);
  }
  int f0 = (r0 < KK), f1 = (r1 < KK);
  int c = f0 + f1;
  scnt[threadIdx.x] = c;
  __syncthreads();
  for (int off=1; off<1024; off<<=1){
    int add = (threadIdx.x >= off) ? scnt[threadIdx.x - off] : 0;
    __syncthreads();
    scnt[threadIdx.x] += add;
    __syncthreads();
  }
  int pos = scnt[threadIdx.x] - c;        // exclusive prefix
  if (f0) idxout[b*KK + pos++] = i0;
  if (f1) idxout[b*KK + pos]   = i0+1;
}

// --------------------------------------- gather + BatchNorm + write idx
__global__ __launch_bounds__(256) void final_kernel(const float* __restrict__ rb,
    const int* __restrict__ idx, const float* __restrict__ g, const float* __restrict__ bt,
    const float* __restrict__ mean, const float* __restrict__ var,
    float* __restrict__ out, int KK){
  int row = blockIdx.x*4 + (threadIdx.x>>6);
  int lane = threadIdx.x & 63;
  int total = NBATCH*KK;
  if (row < total){
    int b = row / KK;
    int src = idx[row];
    float4 v  = *(const float4*)(rb + ((size_t)(b*SEQ+src))*DM + lane*4);
    float4 gm = *(const float4*)(mean + lane*4);
    float4 gv = *(const float4*)(var  + lane*4);
    float4 gg = *(const float4*)(g    + lane*4);
    float4 gb = *(const float4*)(bt   + lane*4);
    float4 o;
    o.x = (v.x-gm.x)*rsqrtf(gv.x+1e-3f)*gg.x + gb.x;
    o.y = (v.y-gm.y)*rsqrtf(gv.y+1e-3f)*gg.y + gb.y;
    o.z = (v.z-gm.z)*rsqrtf(gv.z+1e-3f)*gg.z + gb.z;
    o.w = (v.w-gm.w)*rsqrtf(gv.w+1e-3f)*gg.w + gb.w;
    *(float4*)(out + (size_t)row*DM + lane*4) = o;
  }
  int gid = blockIdx.x*256 + threadIdx.x;
  if (gid < total) out[(size_t)total*DM + gid] = (float)idx[gid];
}

// ================================================================== launch
extern "C" void kernel_launch(void* const* d_in, const int* in_sizes, int n_in,
                              void* d_out, int out_size, void* d_ws, size_t ws_size,
                              hipStream_t stream){
  (void)in_sizes; (void)n_in; (void)ws_size;
  const float* x    = (const float*)d_in[0];
  const float* ln1g = (const float*)d_in[1];
  const float* ln1b = (const float*)d_in[2];
  const float* ln2g = (const float*)d_in[3];
  const float* ln2b = (const float*)d_in[4];
  const float* ln3g = (const float*)d_in[5];
  const float* ln3b = (const float*)d_in[6];
  const float* gqw = (const float*)d_in[7];  const float* gqb = (const float*)d_in[8];
  const float* gkw = (const float*)d_in[9];  const float* gkb = (const float*)d_in[10];
  const float* gvw = (const float*)d_in[11]; const float* gvb = (const float*)d_in[12];
  const float* gow = (const float*)d_in[13]; const float* gob = (const float*)d_in[14];
  const float* lqw = (const float*)d_in[15]; const float* lqb = (const float*)d_in[16];
  const float* lkw = (const float*)d_in[17]; const float* lkb = (const float*)d_in[18];
  const float* lvw = (const float*)d_in[19]; const float* lvb = (const float*)d_in[20];
  const float* low = (const float*)d_in[21]; const float* lob = (const float*)d_in[22];
  const float* fw1 = (const float*)d_in[23]; const float* fb1 = (const float*)d_in[24];
  const float* fw2 = (const float*)d_in[25]; const float* fb2 = (const float*)d_in[26];
  const float* resw = (const float*)d_in[27]; const float* resb = (const float*)d_in[28];
  const float* bng = (const float*)d_in[29]; const float* bnb = (const float*)d_in[30];
  const float* bnm = (const float*)d_in[31]; const float* bnv = (const float*)d_in[32];

  float* ws = (float*)d_ws;
  const size_t M1 = 2097152;                 // B*S*D floats
  float* nb  = ws;            // normed input (reused ln1/ln2/ln3)
  float* qb  = ws + 1*M1;
  float* kb  = ws + 2*M1;
  float* vb  = ws + 3*M1;
  float* ob  = ws + 4*M1;
  float* r1  = ws + 5*M1;     // out1
  float* r2  = ws + 6*M1;     // out2
  float* r3  = ws + 7*M1;     // out3 (then +res proj)
  float* big = ws + 8*M1;     // 4*M1: opart during attention / h1 during FFN
  float* Ms   = ws + 12*M1;
  float* Ls   = Ms + 262144;
  float* colG = Ls + 262144;
  float* colL = colG + 524288;
  float* impb = colL + 524288;
  int*   idxb = (int*)(impb + 8192);

  int KK = out_size / (NBATCH*(DM+1));       // out_size = B*K*(D+1)
  float* out = (float*)d_out;

  // ---- block 1: global attention
  ln_kernel<<<2048,256,0,stream>>>(x, ln1g, ln1b, nb);
  gemm_kernel<<<512,256,0,stream>>>(nb, gqw, gqb, nullptr, qb, 8192,256,256,0);
  gemm_kernel<<<512,256,0,stream>>>(nb, gkw, gkb, nullptr, kb, 8192,256,256,0);
  gemm_kernel<<<512,256,0,stream>>>(nb, gvw, gvb, nullptr, vb, 8192,256,256,0);
  attn_stats_kernel<<<1024,256,0,stream>>>(qb, kb, Ms, Ls);
  attn_pass2_kernel<<<1024,256,0,stream>>>(qb, kb, vb, Ms, Ls, big, colG);
  oreduce_kernel<<<2048,256,0,stream>>>(big, ob);
  gemm_kernel<<<512,256,0,stream>>>(ob, gow, gob, x, r1, 8192,256,256,0);   // out1 = x + attn

  // ---- block 2: local attention
  ln_kernel<<<2048,256,0,stream>>>(r1, ln2g, ln2b, nb);
  gemm_kernel<<<512,256,0,stream>>>(nb, lqw, lqb, nullptr, qb, 8192,256,256,0);
  gemm_kernel<<<512,256,0,stream>>>(nb, lkw, lkb, nullptr, kb, 8192,256,256,0);
  gemm_kernel<<<512,256,0,stream>>>(nb, lvw, lvb, nullptr, vb, 8192,256,256,0);
  attn_stats_kernel<<<1024,256,0,stream>>>(qb, kb, Ms, Ls);
  attn_pass2_kernel<<<1024,256,0,stream>>>(qb, kb, vb, Ms, Ls, big, colL);
  oreduce_kernel<<<2048,256,0,stream>>>(big, ob);
  gemm_kernel<<<512,256,0,stream>>>(ob, low, lob, r1, r2, 8192,256,256,0);  // out2

  // ---- FFN
  ln_kernel<<<2048,256,0,stream>>>(r2, ln3g, ln3b, nb);
  gemm_kernel<<<2048,256,0,stream>>>(nb, fw1, fb1, nullptr, big, 8192,1024,256,1);  // relu
  gemm_kernel<<<512,256,0,stream>>>(big, fw2, fb2, r2, r3, 8192,256,1024,0);        // out3

  // ---- residual projection folded in: r3 = out3 + x@res_w + res_b
  gemm_kernel<<<512,256,0,stream>>>(x, resw, resb, r3, r3, 8192,256,256,0);

  // ---- importance -> top-K -> gather + BN + idx
  imp_kernel<<<32,256,0,stream>>>(colG, colL, impb);
  topk_kernel<<<NBATCH,1024,0,stream>>>(impb, KK, idxb);
  int total = NBATCH*KK;
  final_kernel<<<(total+3)/4,256,0,stream>>>(r3, idxb, bng, bnb, bnm, bnv, out, KK);
}

// Round 2
// 1153.278 us; speedup vs baseline: 1.9711x; 1.9711x over previous
//
#include <hip/hip_runtime.h>

#define SEQ 2048
#define DM 256
#define NH 8
#define DKH 32
#define NBATCH 4
#define SCALE 0.17677669529663687f

typedef __attribute__((ext_vector_type(8))) __bf16 bf16x8;
typedef __attribute__((ext_vector_type(4))) float floatx4;
typedef __attribute__((ext_vector_type(8))) short short8v;

__device__ inline unsigned short f2bf(float x){
  union { float f; unsigned u; } v; v.f = x;
  unsigned r = v.u + 0x7FFFu + ((v.u >> 16) & 1u);
  return (unsigned short)(r >> 16);
}

// ---------------------------------------------------------------- LayerNorm
__global__ __launch_bounds__(256) void ln_kernel(const float* __restrict__ X,
    const float* __restrict__ G, const float* __restrict__ Bv, float* __restrict__ Y){
  int row = blockIdx.x*4 + (threadIdx.x>>6);
  int lane = threadIdx.x & 63;
  const float4 v = *(const float4*)(X + (size_t)row*DM + lane*4);
  float s = v.x+v.y+v.z+v.w;
  #pragma unroll
  for (int off=32; off; off>>=1) s += __shfl_xor(s, off, 64);
  float mean = s * (1.0f/DM);
  float dx=v.x-mean, dy=v.y-mean, dz=v.z-mean, dw=v.w-mean;
  float ss = dx*dx+dy*dy+dz*dz+dw*dw;
  #pragma unroll
  for (int off=32; off; off>>=1) ss += __shfl_xor(ss, off, 64);
  float r = rsqrtf(ss*(1.0f/DM) + 1e-6f);
  const float4 g = *(const float4*)(G + lane*4);
  const float4 b = *(const float4*)(Bv + lane*4);
  float4 o;
  o.x = dx*r*g.x + b.x;
  o.y = dy*r*g.y + b.y;
  o.z = dz*r*g.z + b.z;
  o.w = dw*r*g.w + b.w;
  *(float4*)(Y + (size_t)row*DM + lane*4) = o;
}

// ---------------------------------------------------------------- fp32 GEMM
__global__ __launch_bounds__(256) void gemm_kernel(const float* __restrict__ A,
    const float* __restrict__ Bm, const float* __restrict__ bias,
    const float* __restrict__ Res, float* __restrict__ C,
    int M, int N, int K, int relu){
  __shared__ float sA[16][68];
  __shared__ float sB[16][68];
  int nbk = N >> 6;
  int bx = blockIdx.x % nbk;
  int by = blockIdx.x / nbk;
  int m0 = by << 6, n0 = bx << 6;
  int tx = threadIdx.x & 15, ty = threadIdx.x >> 4;
  int alr = threadIdx.x >> 2;
  int alc = (threadIdx.x & 3) << 2;
  int blr = threadIdx.x >> 4;
  int blc = (threadIdx.x & 15) << 2;
  float acc[4][4] = {{0.f}};
  for (int k0=0; k0<K; k0+=16){
    float4 a  = *(const float4*)&A [(size_t)(m0+alr)*K + k0 + alc];
    float4 bq = *(const float4*)&Bm[(size_t)(k0+blr)*N + n0 + blc];
    __syncthreads();
    sA[alc+0][alr]=a.x; sA[alc+1][alr]=a.y; sA[alc+2][alr]=a.z; sA[alc+3][alr]=a.w;
    *(float4*)&sB[blr][blc] = bq;
    __syncthreads();
    #pragma unroll
    for (int kk=0;kk<16;++kk){
      float4 av = *(const float4*)&sA[kk][ty<<2];
      float4 bv = *(const float4*)&sB[kk][tx<<2];
      acc[0][0]+=av.x*bv.x; acc[0][1]+=av.x*bv.y; acc[0][2]+=av.x*bv.z; acc[0][3]+=av.x*bv.w;
      acc[1][0]+=av.y*bv.x; acc[1][1]+=av.y*bv.y; acc[1][2]+=av.y*bv.z; acc[1][3]+=av.y*bv.w;
      acc[2][0]+=av.z*bv.x; acc[2][1]+=av.z*bv.y; acc[2][2]+=av.z*bv.z; acc[2][3]+=av.z*bv.w;
      acc[3][0]+=av.w*bv.x; acc[3][1]+=av.w*bv.y; acc[3][2]+=av.w*bv.z; acc[3][3]+=av.w*bv.w;
    }
  }
  float4 bb;
  if (bias) bb = *(const float4*)&bias[n0+(tx<<2)];
  else { bb.x=0.f; bb.y=0.f; bb.z=0.f; bb.w=0.f; }
  #pragma unroll
  for (int i=0;i<4;++i){
    size_t row = (size_t)m0 + (ty<<2) + i;
    float4 o;
    o.x=acc[i][0]+bb.x; o.y=acc[i][1]+bb.y; o.z=acc[i][2]+bb.z; o.w=acc[i][3]+bb.w;
    if (Res){
      float4 rr = *(const float4*)&Res[row*N + n0+(tx<<2)];
      o.x+=rr.x; o.y+=rr.y; o.z+=rr.z; o.w+=rr.w;
    }
    if (relu){
      o.x=fmaxf(o.x,0.f); o.y=fmaxf(o.y,0.f); o.z=fmaxf(o.z,0.f); o.w=fmaxf(o.w,0.f);
    }
    *(float4*)&C[row*N + n0+(tx<<2)] = o;
  }
}

// ----------------------------------------------- fp32 -> bf16 (opt. scale)
__global__ __launch_bounds__(256) void cvt_kernel(const float* __restrict__ src,
    unsigned short* __restrict__ dst, float scale, int n4){
  int i = blockIdx.x*256 + threadIdx.x;
  if (i >= n4) return;
  float4 v = ((const float4*)src)[i];
  ushort4 o;
  o.x = f2bf(v.x*scale); o.y = f2bf(v.y*scale);
  o.z = f2bf(v.z*scale); o.w = f2bf(v.w*scale);
  ((ushort4*)dst)[i] = o;
}

// ------------------------------------------------ fused flash MFMA attention
// grid = 32 qblocks x 32 (b,h); block 256 = 4 waves; wave = 16 q rows.
// Q is pre-scaled by SCALE. Outputs O (fp32), per-row m and 1/l.
__global__ __launch_bounds__(256) void flash_kernel(
    const unsigned short* __restrict__ Qb, const unsigned short* __restrict__ Kb,
    const unsigned short* __restrict__ Vb, float* __restrict__ O,
    float* __restrict__ Mout, float* __restrict__ Lout){
  __shared__ unsigned short sK[32*32];      // [key][dk]
  __shared__ unsigned short sVt[32*32];     // [d][key]  (transposed)
  __shared__ unsigned short sP[4*16*32];    // per-wave [q][key]
  int qb = blockIdx.x & 31, bh = blockIdx.x >> 5;
  int h = bh & 7, b = bh >> 3;
  int tid = threadIdx.x, w = tid >> 6, lane = tid & 63;
  int m16 = lane & 15, quad = lane >> 4;
  int qrow0 = qb*64 + w*16;

  // Q A-fragment: A[m=lane&15][k=quad*8+j]
  bf16x8 qfrag = *(const bf16x8*)(Qb + (size_t)(b*SEQ + qrow0 + m16)*DM + h*DKH + quad*8);

  floatx4 o0 = {0.f,0.f,0.f,0.f}, o1 = {0.f,0.f,0.f,0.f};
  float ms[4], ls[4];
  #pragma unroll
  for (int r=0;r<4;++r){ ms[r] = -__builtin_inff(); ls[r] = 0.f; }
  unsigned short* sPw = sP + w*512;

  for (int t0=0; t0<SEQ; t0+=32){
    __syncthreads();
    if (tid < 128){
      int row = tid >> 2, c8 = (tid & 3)*8;
      short8v kk = *(const short8v*)(Kb + (size_t)(b*SEQ + t0 + row)*DM + h*DKH + c8);
      *(short8v*)(sK + row*32 + c8) = kk;
    } else {
      int t2 = tid - 128;
      int row = t2 >> 2, c8 = (t2 & 3)*8;
      short8v vv = *(const short8v*)(Vb + (size_t)(b*SEQ + t0 + row)*DM + h*DKH + c8);
      union { short8v v; unsigned short u[8]; } uv; uv.v = vv;
      #pragma unroll
      for (int j=0;j<8;++j) sVt[(c8+j)*32 + row] = uv.u[j];
    }
    __syncthreads();

    // S = Q.K^T : B[k=dk][n=key], lane n=m16, k=quad*8+j -> sK rows contiguous
    bf16x8 kb0 = *(const bf16x8*)(sK + m16*32 + quad*8);
    bf16x8 kb1 = *(const bf16x8*)(sK + (16+m16)*32 + quad*8);
    floatx4 z = {0.f,0.f,0.f,0.f};
    floatx4 s0 = __builtin_amdgcn_mfma_f32_16x16x32_bf16(qfrag, kb0, z, 0,0,0);
    floatx4 s1 = __builtin_amdgcn_mfma_f32_16x16x32_bf16(qfrag, kb1, z, 0,0,0);

    #pragma unroll
    for (int r=0;r<4;++r){
      float t = fmaxf(s0[r], s1[r]);
      t = fmaxf(t, __shfl_xor(t, 1, 64));
      t = fmaxf(t, __shfl_xor(t, 2, 64));
      t = fmaxf(t, __shfl_xor(t, 4, 64));
      t = fmaxf(t, __shfl_xor(t, 8, 64));
      float mn = fmaxf(ms[r], t);
      float a  = __expf(ms[r] - mn);
      float p0 = __expf(s0[r] - mn);
      float p1 = __expf(s1[r] - mn);
      float rs = p0 + p1;
      rs += __shfl_xor(rs, 1, 64);
      rs += __shfl_xor(rs, 2, 64);
      rs += __shfl_xor(rs, 4, 64);
      rs += __shfl_xor(rs, 8, 64);
      ls[r] = ls[r]*a + rs;
      ms[r] = mn;
      o0[r] *= a; o1[r] *= a;
      int prow = quad*4 + r;
      sPw[prow*32 + m16]      = f2bf(p0);
      sPw[prow*32 + 16 + m16] = f2bf(p1);
    }
    // P A-frag (same-wave LDS RAW: compiler orders via lgkmcnt)
    bf16x8 pfrag = *(const bf16x8*)(sPw + m16*32 + quad*8);
    // V B-frags: B[k=key][n=d], lane n=m16 -> sVt rows contiguous
    bf16x8 vb0 = *(const bf16x8*)(sVt + m16*32 + quad*8);
    bf16x8 vb1 = *(const bf16x8*)(sVt + (16+m16)*32 + quad*8);
    o0 = __builtin_amdgcn_mfma_f32_16x16x32_bf16(pfrag, vb0, o0, 0,0,0);
    o1 = __builtin_amdgcn_mfma_f32_16x16x32_bf16(pfrag, vb1, o1, 0,0,0);
  }

  #pragma unroll
  for (int r=0;r<4;++r){
    float inv = 1.0f / ls[r];
    int q = qrow0 + quad*4 + r;
    size_t base = (size_t)(b*SEQ + q)*DM + h*DKH;
    O[base + m16]      = o0[r]*inv;
    O[base + 16 + m16] = o1[r]*inv;
    if (m16 == 0){
      Mout[(size_t)bh*SEQ + q] = ms[r];
      Lout[(size_t)bh*SEQ + q] = inv;
    }
  }
}

// --------------------- column sums of softmax weights (recompute S via MFMA)
// grid = 32 kchunks x 32 (b,h); wave holds 16 keys as A-frag, loops q.
__global__ __launch_bounds__(256) void colsum_kernel(
    const unsigned short* __restrict__ Qb, const unsigned short* __restrict__ Kb,
    const float* __restrict__ Mv, const float* __restrict__ Lv,
    float* __restrict__ col){
  int kc = blockIdx.x & 31, bh = blockIdx.x >> 5;
  int h = bh & 7, b = bh >> 3;
  int lane = threadIdx.x & 63, w = threadIdx.x >> 6;
  int m16 = lane & 15, quad = lane >> 4;
  int kbase = kc*64 + w*16;
  // A = K tile: A[m=key][k=dk]
  bf16x8 kfrag = *(const bf16x8*)(Kb + (size_t)(b*SEQ + kbase + m16)*DM + h*DKH + quad*8);
  float acc[4] = {0.f,0.f,0.f,0.f};
  for (int q0=0; q0<SEQ; q0+=16){
    // B = Q^T: B[k=dk][n=q], lane n=m16
    bf16x8 qf = *(const bf16x8*)(Qb + (size_t)(b*SEQ + q0 + m16)*DM + h*DKH + quad*8);
    floatx4 z = {0.f,0.f,0.f,0.f};
    floatx4 t = __builtin_amdgcn_mfma_f32_16x16x32_bf16(kfrag, qf, z, 0,0,0);
    float mq = Mv[(size_t)bh*SEQ + q0 + m16];
    float lq = Lv[(size_t)bh*SEQ + q0 + m16];
    #pragma unroll
    for (int r=0;r<4;++r) acc[r] += __expf(t[r] - mq) * lq;
  }
  #pragma unroll
  for (int r=0;r<4;++r){
    float v = acc[r];
    v += __shfl_xor(v, 1, 64);
    v += __shfl_xor(v, 2, 64);
    v += __shfl_xor(v, 4, 64);
    v += __shfl_xor(v, 8, 64);
    if (m16 == 0) col[(size_t)bh*SEQ + kbase + quad*4 + r] = v;
  }
}

// ------------------------------------- importance = 0.7*G + 0.3*L (fp64 acc)
__global__ __launch_bounds__(256) void imp_kernel(const float* __restrict__ colG,
    const float* __restrict__ colL, float* __restrict__ imp){
  int i = blockIdx.x*256 + threadIdx.x;   // b*2048 + t
  int b = i >> 11, t = i & 2047;
  double sg = 0.0, sl = 0.0;
  for (int h=0; h<8; ++h){
    sg += (double)colG[(size_t)(b*8+h)*SEQ + t];
    sl += (double)colL[(size_t)(b*8+h)*SEQ + t];
  }
  imp[i] = (float)(0.7*sg + 0.3*sl);
}

// ------------------------- top-K per batch (stable: value desc, index asc)
__global__ __launch_bounds__(1024) void topk_kernel(const float* __restrict__ imp,
    int KK, int* __restrict__ idxout){
  __shared__ float sv[2048];
  __shared__ int scnt[1024];
  int b = blockIdx.x;
  for (int i=threadIdx.x; i<2048; i+=1024) sv[i] = imp[b*2048 + i];
  __syncthreads();
  int i0 = threadIdx.x*2;
  float v0 = sv[i0], v1 = sv[i0+1];
  int r0 = 0, r1 = 0;
  for (int j=0; j<2048; ++j){
    float vj = sv[j];
    r0 += (vj > v0) || (vj == v0 && j < i0);
    r1 += (vj > v1) || (vj == v1 && j < i0+1);
  }
  int f0 = (r0 < KK), f1 = (r1 < KK);
  int c = f0 + f1;
  scnt[threadIdx.x] = c;
  __syncthreads();
  for (int off=1; off<1024; off<<=1){
    int add = (threadIdx.x >= off) ? scnt[threadIdx.x - off] : 0;
    __syncthreads();
    scnt[threadIdx.x] += add;
    __syncthreads();
  }
  int pos = scnt[threadIdx.x] - c;
  if (f0) idxout[b*KK + pos++] = i0;
  if (f1) idxout[b*KK + pos]   = i0+1;
}

// --------------------------------------- gather + BatchNorm + write idx
__global__ __launch_bounds__(256) void final_kernel(const float* __restrict__ rb,
    const int* __restrict__ idx, const float* __restrict__ g, const float* __restrict__ bt,
    const float* __restrict__ mean, const float* __restrict__ var,
    float* __restrict__ out, int KK){
  int row = blockIdx.x*4 + (threadIdx.x>>6);
  int lane = threadIdx.x & 63;
  int total = NBATCH*KK;
  if (row < total){
    int b = row / KK;
    int src = idx[row];
    float4 v  = *(const float4*)(rb + ((size_t)(b*SEQ+src))*DM + lane*4);
    float4 gm = *(const float4*)(mean + lane*4);
    float4 gv = *(const float4*)(var  + lane*4);
    float4 gg = *(const float4*)(g    + lane*4);
    float4 gb = *(const float4*)(bt   + lane*4);
    float4 o;
    o.x = (v.x-gm.x)*rsqrtf(gv.x+1e-3f)*gg.x + gb.x;
    o.y = (v.y-gm.y)*rsqrtf(gv.y+1e-3f)*gg.y + gb.y;
    o.z = (v.z-gm.z)*rsqrtf(gv.z+1e-3f)*gg.z + gb.z;
    o.w = (v.w-gm.w)*rsqrtf(gv.w+1e-3f)*gg.w + gb.w;
    *(float4*)(out + (size_t)row*DM + lane*4) = o;
  }
  int gid = blockIdx.x*256 + threadIdx.x;
  if (gid < total) out[(size_t)total*DM + gid] = (float)idx[gid];
}

// ================================================================== launch
extern "C" void kernel_launch(void* const* d_in, const int* in_sizes, int n_in,
                              void* d_out, int out_size, void* d_ws, size_t ws_size,
                              hipStream_t stream){
  (void)in_sizes; (void)n_in; (void)ws_size;
  const float* x    = (const float*)d_in[0];
  const float* ln1g = (const float*)d_in[1];
  const float* ln1b = (const float*)d_in[2];
  const float* ln2g = (const float*)d_in[3];
  const float* ln2b = (const float*)d_in[4];
  const float* ln3g = (const float*)d_in[5];
  const float* ln3b = (const float*)d_in[6];
  const float* gqw = (const float*)d_in[7];  const float* gqb = (const float*)d_in[8];
  const float* gkw = (const float*)d_in[9];  const float* gkb = (const float*)d_in[10];
  const float* gvw = (const float*)d_in[11]; const float* gvb = (const float*)d_in[12];
  const float* gow = (const float*)d_in[13]; const float* gob = (const float*)d_in[14];
  const float* lqw = (const float*)d_in[15]; const float* lqb = (const float*)d_in[16];
  const float* lkw = (const float*)d_in[17]; const float* lkb = (const float*)d_in[18];
  const float* lvw = (const float*)d_in[19]; const float* lvb = (const float*)d_in[20];
  const float* low = (const float*)d_in[21]; const float* lob = (const float*)d_in[22];
  const float* fw1 = (const float*)d_in[23]; const float* fb1 = (const float*)d_in[24];
  const float* fw2 = (const float*)d_in[25]; const float* fb2 = (const float*)d_in[26];
  const float* resw = (const float*)d_in[27]; const float* resb = (const float*)d_in[28];
  const float* bng = (const float*)d_in[29]; const float* bnb = (const float*)d_in[30];
  const float* bnm = (const float*)d_in[31]; const float* bnv = (const float*)d_in[32];

  float* ws = (float*)d_ws;
  const size_t M1 = 2097152;                 // B*S*D floats
  float* nb  = ws;
  float* qb  = ws + 1*M1;
  float* kb  = ws + 2*M1;
  float* vb  = ws + 3*M1;
  float* ob  = ws + 4*M1;
  float* r1  = ws + 5*M1;
  float* r2  = ws + 6*M1;
  float* r3  = ws + 7*M1;
  float* big = ws + 8*M1;                    // FFN h1 (8192x1024) later
  // bf16 Q/K/V overlay the big region (used only during attention phase)
  unsigned short* qbf = (unsigned short*)(ws + 8*M1);
  unsigned short* kbf = (unsigned short*)(ws + 8*M1 + M1/2);
  unsigned short* vbf = (unsigned short*)(ws + 9*M1);
  float* Ms   = ws + 12*M1;                  // 32*2048
  float* Ls   = Ms + 65536;
  float* colG = Ls + 65536;
  float* colL = colG + 65536;
  float* impb = colL + 65536;
  int*   idxb = (int*)(impb + 8192);

  int KK = out_size / (NBATCH*(DM+1));
  float* out = (float*)d_out;
  const int n4 = (int)(M1/4);

  // ---- block 1: global attention
  ln_kernel<<<2048,256,0,stream>>>(x, ln1g, ln1b, nb);
  gemm_kernel<<<512,256,0,stream>>>(nb, gqw, gqb, nullptr, qb, 8192,256,256,0);
  gemm_kernel<<<512,256,0,stream>>>(nb, gkw, gkb, nullptr, kb, 8192,256,256,0);
  gemm_kernel<<<512,256,0,stream>>>(nb, gvw, gvb, nullptr, vb, 8192,256,256,0);
  cvt_kernel<<<2048,256,0,stream>>>(qb, qbf, SCALE, n4);
  cvt_kernel<<<2048,256,0,stream>>>(kb, kbf, 1.0f, n4);
  cvt_kernel<<<2048,256,0,stream>>>(vb, vbf, 1.0f, n4);
  flash_kernel<<<1024,256,0,stream>>>(qbf, kbf, vbf, ob, Ms, Ls);
  colsum_kernel<<<1024,256,0,stream>>>(qbf, kbf, Ms, Ls, colG);
  gemm_kernel<<<512,256,0,stream>>>(ob, gow, gob, x, r1, 8192,256,256,0);

  // ---- block 2: local attention
  ln_kernel<<<2048,256,0,stream>>>(r1, ln2g, ln2b, nb);
  gemm_kernel<<<512,256,0,stream>>>(nb, lqw, lqb, nullptr, qb, 8192,256,256,0);
  gemm_kernel<<<512,256,0,stream>>>(nb, lkw, lkb, nullptr, kb, 8192,256,256,0);
  gemm_kernel<<<512,256,0,stream>>>(nb, lvw, lvb, nullptr, vb, 8192,256,256,0);
  cvt_kernel<<<2048,256,0,stream>>>(qb, qbf, SCALE, n4);
  cvt_kernel<<<2048,256,0,stream>>>(kb, kbf, 1.0f, n4);
  cvt_kernel<<<2048,256,0,stream>>>(vb, vbf, 1.0f, n4);
  flash_kernel<<<1024,256,0,stream>>>(qbf, kbf, vbf, ob, Ms, Ls);
  colsum_kernel<<<1024,256,0,stream>>>(qbf, kbf, Ms, Ls, colL);
  gemm_kernel<<<512,256,0,stream>>>(ob, low, lob, r1, r2, 8192,256,256,0);

  // ---- FFN
  ln_kernel<<<2048,256,0,stream>>>(r2, ln3g, ln3b, nb);
  gemm_kernel<<<2048,256,0,stream>>>(nb, fw1, fb1, nullptr, big, 8192,1024,256,1);
  gemm_kernel<<<512,256,0,stream>>>(big, fw2, fb2, r2, r3, 8192,256,1024,0);

  // ---- residual projection folded in
  gemm_kernel<<<512,256,0,stream>>>(x, resw, resb, r3, r3, 8192,256,256,0);

  // ---- importance -> top-K -> gather + BN + idx
  imp_kernel<<<32,256,0,stream>>>(colG, colL, impb);
  topk_kernel<<<NBATCH,1024,0,stream>>>(impb, KK, idxb);
  int total = NBATCH*KK;
  final_kernel<<<(total+3)/4,256,0,stream>>>(r3, idxb, bng, bnb, bnm, bnv, out, KK);
}

// Round 3
// 682.461 us; speedup vs baseline: 3.3309x; 1.6899x over previous
//
#include <hip/hip_runtime.h>

#define SEQ 2048
#define DM 256
#define NH 8
#define DKH 32
#define NBATCH 4
#define SCALE 0.17677669529663687f

typedef __attribute__((ext_vector_type(8))) __bf16 bf16x8;
typedef __attribute__((ext_vector_type(4))) float floatx4;
typedef __attribute__((ext_vector_type(8))) short short8v;

__device__ inline unsigned short f2bf(float x){
  union { float f; unsigned u; } v; v.f = x;
  unsigned r = v.u + 0x7FFFu + ((v.u >> 16) & 1u);
  return (unsigned short)(r >> 16);
}

// ------------------------------------------- LayerNorm fp32 in -> bf16 out
__global__ __launch_bounds__(256) void ln_kernel(const float* __restrict__ X,
    const float* __restrict__ G, const float* __restrict__ Bv,
    unsigned short* __restrict__ Y){
  int row = blockIdx.x*4 + (threadIdx.x>>6);
  int lane = threadIdx.x & 63;
  const float4 v = *(const float4*)(X + (size_t)row*DM + lane*4);
  float s = v.x+v.y+v.z+v.w;
  #pragma unroll
  for (int off=32; off; off>>=1) s += __shfl_xor(s, off, 64);
  float mean = s * (1.0f/DM);
  float dx=v.x-mean, dy=v.y-mean, dz=v.z-mean, dw=v.w-mean;
  float ss = dx*dx+dy*dy+dz*dz+dw*dw;
  #pragma unroll
  for (int off=32; off; off>>=1) ss += __shfl_xor(ss, off, 64);
  float r = rsqrtf(ss*(1.0f/DM) + 1e-6f);
  const float4 g = *(const float4*)(G + lane*4);
  const float4 b = *(const float4*)(Bv + lane*4);
  ushort4 o;
  o.x = f2bf(dx*r*g.x + b.x);
  o.y = f2bf(dy*r*g.y + b.y);
  o.z = f2bf(dz*r*g.z + b.z);
  o.w = f2bf(dw*r*g.w + b.w);
  *(ushort4*)(Y + (size_t)row*DM + lane*4) = o;
}

// ----------------------------------------------- fp32 -> bf16 plain convert
__global__ __launch_bounds__(256) void cvt_kernel(const float* __restrict__ src,
    unsigned short* __restrict__ dst, int n4){
  int i = blockIdx.x*256 + threadIdx.x;
  if (i >= n4) return;
  float4 v = ((const float4*)src)[i];
  ushort4 o;
  o.x = f2bf(v.x); o.y = f2bf(v.y); o.z = f2bf(v.z); o.w = f2bf(v.w);
  ((ushort4*)dst)[i] = o;
}

// --------------------------- weight transpose+convert: fp32 [K][N] -> bf16 [N][K]
__global__ __launch_bounds__(256) void wtrans_kernel(const float* __restrict__ W,
    unsigned short* __restrict__ Wt, int K, int N){
  __shared__ unsigned short sT[64][40];      // [n][k] tile, 80B rows (16B-aligned)
  int nbk = N >> 6;
  int bx = blockIdx.x % nbk, by = blockIdx.x / nbk;
  int k0 = by << 5, n0 = bx << 6;
  int tid = threadIdx.x;
  int r = tid >> 3, cs = (tid & 7) << 3;     // k-row 0..31, n-col base 0..56
  const float* ip = W + (size_t)(k0+r)*N + n0 + cs;
  float4 a = *(const float4*)ip;
  float4 bq = *(const float4*)(ip+4);
  sT[cs+0][r]=f2bf(a.x); sT[cs+1][r]=f2bf(a.y); sT[cs+2][r]=f2bf(a.z); sT[cs+3][r]=f2bf(a.w);
  sT[cs+4][r]=f2bf(bq.x); sT[cs+5][r]=f2bf(bq.y); sT[cs+6][r]=f2bf(bq.z); sT[cs+7][r]=f2bf(bq.w);
  __syncthreads();
  int n = tid >> 2, kc = (tid & 3) << 3;     // n 0..63, k-chunk 0,8,16,24
  *(short8v*)(Wt + (size_t)(n0+n)*K + k0 + kc) = *(const short8v*)(&sT[n][kc]);
}

// ------------------- V bf16 [b*S][256] -> Vt bf16 [(b*8+h)*32+d][S]
__global__ __launch_bounds__(256) void vtrans_kernel(const unsigned short* __restrict__ V,
    unsigned short* __restrict__ Vt){
  __shared__ unsigned short sT[32][136];     // [d][key], 272B rows (16B-aligned)
  int kt = blockIdx.x & 15, bh = blockIdx.x >> 4;
  int h = bh & 7, b = bh >> 3;
  int t0 = kt << 7;
  int tid = threadIdx.x;
  int key = tid >> 1, half = (tid & 1) << 4;
  const unsigned short* vp = V + (size_t)(b*SEQ + t0 + key)*DM + h*DKH + half;
  union {short8v v; unsigned short u[8];} ua, ub;
  ua.v = *(const short8v*)vp;
  ub.v = *(const short8v*)(vp+8);
  #pragma unroll
  for (int j=0;j<8;++j){ sT[half+j][key] = ua.u[j]; sT[half+8+j][key] = ub.u[j]; }
  __syncthreads();
  int d = tid >> 3, kc = (tid & 7) << 4;
  unsigned short* op = Vt + (size_t)(bh*DKH + d)*SEQ + t0 + kc;
  *(short8v*)op     = *(const short8v*)(&sT[d][kc]);
  *(short8v*)(op+8) = *(const short8v*)(&sT[d][kc+8]);
}

// ---------------------------------------------------------- bf16 MFMA GEMM
// C[M,N] = A[M,K] @ Bt[N,K]^T + bias (+Res fp32) (opt relu) (opt *outscale)
// 128x64 tile, BK=64, 4 waves (2x2), fragment-ordered LDS (conflict-free).
// flags: 1 = relu, 2 = bf16 output
__global__ __launch_bounds__(256) void gemm_bf16(const unsigned short* __restrict__ A,
    const unsigned short* __restrict__ Bt, const float* __restrict__ bias,
    const float* __restrict__ Res, void* __restrict__ Cout,
    int M, int N, int K, int flags, float outscale){
  __shared__ unsigned short sA[8192];        // 1024 chunks * 8 shorts
  __shared__ unsigned short sB[4096];        // 512 chunks
  int nbk = N >> 6;
  int bx = blockIdx.x % nbk, by = blockIdx.x / nbk;
  int m0 = by << 7, n0 = bx << 6;
  int tid = threadIdx.x, w = tid >> 6, lane = tid & 63;
  int m16 = lane & 15, quad = lane >> 4;
  int wr = w & 1, wc = w >> 1;
  floatx4 acc[4][2];
  #pragma unroll
  for (int i=0;i<4;++i){ acc[i][0]=(floatx4){0,0,0,0}; acc[i][1]=(floatx4){0,0,0,0}; }
  for (int k0=0; k0<K; k0+=64){
    __syncthreads();
    #pragma unroll
    for (int i=0;i<4;++i){
      int c = tid + i*256;
      int l = c & 63, kk = (c>>6)&1, mt = c>>7;
      int row = m0 + mt*16 + (l&15);
      int col = k0 + kk*32 + ((l>>4)<<3);
      *(short8v*)(sA + c*8) = *(const short8v*)(A + (size_t)row*K + col);
    }
    #pragma unroll
    for (int i=0;i<2;++i){
      int c = tid + i*256;
      int l = c & 63, kk = (c>>6)&1, nt = c>>7;
      int row = n0 + nt*16 + (l&15);
      int col = k0 + kk*32 + ((l>>4)<<3);
      *(short8v*)(sB + c*8) = *(const short8v*)(Bt + (size_t)row*K + col);
    }
    __syncthreads();
    #pragma unroll
    for (int kk=0;kk<2;++kk){
      bf16x8 bf0 = *(const bf16x8*)(sB + (((wc*2+0)*2+kk)*64 + lane)*8);
      bf16x8 bf1 = *(const bf16x8*)(sB + (((wc*2+1)*2+kk)*64 + lane)*8);
      #pragma unroll
      for (int mt=0;mt<4;++mt){
        bf16x8 af = *(const bf16x8*)(sA + (((wr*4+mt)*2+kk)*64 + lane)*8);
        acc[mt][0] = __builtin_amdgcn_mfma_f32_16x16x32_bf16(af, bf0, acc[mt][0], 0,0,0);
        acc[mt][1] = __builtin_amdgcn_mfma_f32_16x16x32_bf16(af, bf1, acc[mt][1], 0,0,0);
      }
    }
  }
  float b0 = bias ? bias[n0 + wc*32 + m16]      : 0.0f;
  float b1 = bias ? bias[n0 + wc*32 + 16 + m16] : 0.0f;
  #pragma unroll
  for (int mt=0;mt<4;++mt){
    #pragma unroll
    for (int r=0;r<4;++r){
      size_t row = (size_t)m0 + wr*64 + mt*16 + quad*4 + r;
      int col0 = n0 + wc*32 + m16, col1 = col0 + 16;
      float v0 = acc[mt][0][r] + b0, v1 = acc[mt][1][r] + b1;
      if (Res){ v0 += Res[row*N + col0]; v1 += Res[row*N + col1]; }
      if (flags & 1){ v0 = fmaxf(v0, 0.0f); v1 = fmaxf(v1, 0.0f); }
      v0 *= outscale; v1 *= outscale;
      if (flags & 2){
        unsigned short* C = (unsigned short*)Cout;
        C[row*N + col0] = f2bf(v0); C[row*N + col1] = f2bf(v1);
      } else {
        float* C = (float*)Cout;
        C[row*N + col0] = v0; C[row*N + col1] = v1;
      }
    }
  }
}

// ------------------------------------------------ fused flash MFMA attention
// grid = 32 qblocks x 32 (b,h); 4 waves; wave = 16 q rows; 128-key tiles.
// Q pre-scaled. sK/sV/sP fragment-ordered (conflict-free b128). Outputs bf16 O,
// per-row m and 1/l.
__global__ __launch_bounds__(256) void flash_kernel(
    const unsigned short* __restrict__ Qb, const unsigned short* __restrict__ Kb,
    const unsigned short* __restrict__ Vt, unsigned short* __restrict__ Obf,
    float* __restrict__ Mout, float* __restrict__ Lout){
  __shared__ unsigned short sK[4096];        // (kt*64+lane)*8 : key=kt*16+(l&15), dk=(l>>4)*8+j
  __shared__ unsigned short sV[4096];        // ((ks*2+nt)*64+lane)*8 : d=nt*16+(l&15), key=ks*32+(l>>4)*8+j
  __shared__ unsigned short sP[4*2048];      // per-wave frag-order: (ks*64+lane)*8
  int qb = blockIdx.x & 31, bh = blockIdx.x >> 5;
  int h = bh & 7, b = bh >> 3;
  int tid = threadIdx.x, w = tid >> 6, lane = tid & 63;
  int m16 = lane & 15, quad = lane >> 4;
  int qrow0 = qb*64 + w*16;
  bf16x8 qfrag = *(const bf16x8*)(Qb + (size_t)(b*SEQ + qrow0 + m16)*DM + h*DKH + quad*8);
  floatx4 o0 = {0,0,0,0}, o1 = {0,0,0,0};
  float ms[4], ls[4];
  #pragma unroll
  for (int r=0;r<4;++r){ ms[r] = -__builtin_inff(); ls[r] = 0.0f; }
  unsigned short* sPw = sP + w*2048;
  // sP write-index constants: idx = kt*256 + (A+B+r)*8 + C  (verified round-trip)
  int wA = quad*4, wB = (m16>>3)*16, wC = m16&7;
  int wbase = (wA + wB)*8 + wC;

  for (int t0=0; t0<SEQ; t0+=128){
    __syncthreads();
    #pragma unroll
    for (int i=0;i<2;++i){
      int c = tid + i*256;
      int l = c & 63;
      { // K chunk
        int kt = c >> 6;
        int key = t0 + kt*16 + (l&15);
        int dc = (l>>4)<<3;
        *(short8v*)(sK + c*8) = *(const short8v*)(Kb + (size_t)(b*SEQ+key)*DM + h*DKH + dc);
      }
      { // V chunk
        int nt = (c>>6)&1, ks = c>>7;
        int d = nt*16 + (l&15);
        int ko = ks*32 + ((l>>4)<<3);
        *(short8v*)(sV + c*8) = *(const short8v*)(Vt + (size_t)(bh*DKH + d)*SEQ + t0 + ko);
      }
    }
    __syncthreads();
    floatx4 z = {0,0,0,0};
    floatx4 s[8];
    #pragma unroll
    for (int kt=0;kt<8;++kt){
      bf16x8 kf = *(const bf16x8*)(sK + (kt*64+lane)*8);
      s[kt] = __builtin_amdgcn_mfma_f32_16x16x32_bf16(qfrag, kf, z, 0,0,0);
    }
    #pragma unroll
    for (int r=0;r<4;++r){
      float mx = s[0][r];
      #pragma unroll
      for (int kt=1;kt<8;++kt) mx = fmaxf(mx, s[kt][r]);
      mx = fmaxf(mx, __shfl_xor(mx, 1, 64));
      mx = fmaxf(mx, __shfl_xor(mx, 2, 64));
      mx = fmaxf(mx, __shfl_xor(mx, 4, 64));
      mx = fmaxf(mx, __shfl_xor(mx, 8, 64));
      float mn = fmaxf(ms[r], mx);
      float a  = __expf(ms[r] - mn);
      float p[8]; float rs = 0.0f;
      #pragma unroll
      for (int kt=0;kt<8;++kt){ p[kt] = __expf(s[kt][r] - mn); rs += p[kt]; }
      rs += __shfl_xor(rs, 1, 64);
      rs += __shfl_xor(rs, 2, 64);
      rs += __shfl_xor(rs, 4, 64);
      rs += __shfl_xor(rs, 8, 64);
      ls[r] = ls[r]*a + rs;
      ms[r] = mn;
      o0[r] *= a; o1[r] *= a;
      #pragma unroll
      for (int kt=0;kt<8;++kt) sPw[kt*256 + wbase + r*8] = f2bf(p[kt]);
    }
    #pragma unroll
    for (int ks=0;ks<4;++ks){
      bf16x8 pf  = *(const bf16x8*)(sPw + (ks*64+lane)*8);
      bf16x8 vf0 = *(const bf16x8*)(sV + ((ks*2+0)*64+lane)*8);
      bf16x8 vf1 = *(const bf16x8*)(sV + ((ks*2+1)*64+lane)*8);
      o0 = __builtin_amdgcn_mfma_f32_16x16x32_bf16(pf, vf0, o0, 0,0,0);
      o1 = __builtin_amdgcn_mfma_f32_16x16x32_bf16(pf, vf1, o1, 0,0,0);
    }
  }
  #pragma unroll
  for (int r=0;r<4;++r){
    float inv = 1.0f / ls[r];
    int q = qrow0 + quad*4 + r;
    size_t base = (size_t)(b*SEQ + q)*DM + h*DKH;
    Obf[base + m16]      = f2bf(o0[r]*inv);
    Obf[base + 16 + m16] = f2bf(o1[r]*inv);
    if (m16 == 0){
      Mout[(size_t)bh*SEQ + q] = ms[r];
      Lout[(size_t)bh*SEQ + q] = inv;
    }
  }
}

// --------------------- column sums of softmax weights (recompute S via MFMA)
// grid = 32 keychunks x 32 (b,h); wave = 16 keys (A-frag, regs); Q/M/L staged in LDS.
__global__ __launch_bounds__(256) void colsum_kernel(
    const unsigned short* __restrict__ Qb, const unsigned short* __restrict__ Kb,
    const float* __restrict__ Mv, const float* __restrict__ Lv,
    float* __restrict__ col){
  __shared__ unsigned short sQ[2048];        // (qt*64+lane)*8 frag-order, 64 q
  __shared__ float sM[64], sL[64];
  int kc = blockIdx.x & 31, bh = blockIdx.x >> 5;
  int h = bh & 7, b = bh >> 3;
  int tid = threadIdx.x, w = tid >> 6, lane = tid & 63;
  int m16 = lane & 15, quad = lane >> 4;
  int key = kc*64 + w*16 + m16;
  bf16x8 kfrag = *(const bf16x8*)(Kb + (size_t)(b*SEQ+key)*DM + h*DKH + quad*8);
  float acc[4] = {0,0,0,0};
  for (int q0=0; q0<SEQ; q0+=64){
    __syncthreads();
    {
      int c = tid;
      int l = c & 63, qt = c >> 6;
      int q = q0 + qt*16 + (l&15);
      int dc = (l>>4)<<3;
      *(short8v*)(sQ + c*8) = *(const short8v*)(Qb + (size_t)(b*SEQ+q)*DM + h*DKH + dc);
      if (tid < 64) sM[tid] = Mv[(size_t)bh*SEQ + q0 + tid];
      else if (tid < 128) sL[tid-64] = Lv[(size_t)bh*SEQ + q0 + tid - 64];
    }
    __syncthreads();
    floatx4 z = {0,0,0,0};
    #pragma unroll
    for (int qt=0;qt<4;++qt){
      bf16x8 qf = *(const bf16x8*)(sQ + (qt*64+lane)*8);
      floatx4 t = __builtin_amdgcn_mfma_f32_16x16x32_bf16(kfrag, qf, z, 0,0,0);
      float mq = sM[qt*16+m16], lq = sL[qt*16+m16];
      #pragma unroll
      for (int r=0;r<4;++r) acc[r] += __expf(t[r]-mq)*lq;
    }
  }
  #pragma unroll
  for (int r=0;r<4;++r){
    float v = acc[r];
    v += __shfl_xor(v, 1, 64);
    v += __shfl_xor(v, 2, 64);
    v += __shfl_xor(v, 4, 64);
    v += __shfl_xor(v, 8, 64);
    if (m16 == 0) col[(size_t)bh*SEQ + kc*64 + w*16 + quad*4 + r] = v;
  }
}

// ------------------------------------- importance = 0.7*G + 0.3*L (fp64 acc)
__global__ __launch_bounds__(256) void imp_kernel(const float* __restrict__ colG,
    const float* __restrict__ colL, float* __restrict__ imp){
  int i = blockIdx.x*256 + threadIdx.x;
  int b = i >> 11, t = i & 2047;
  double sg = 0.0, sl = 0.0;
  for (int h=0; h<8; ++h){
    sg += (double)colG[(size_t)(b*8+h)*SEQ + t];
    sl += (double)colL[(size_t)(b*8+h)*SEQ + t];
  }
  imp[i] = (float)(0.7*sg + 0.3*sl);
}

// ------------------------- top-K per batch (stable: value desc, index asc)
__global__ __launch_bounds__(1024) void topk_kernel(const float* __restrict__ imp,
    int KK, int* __restrict__ idxout){
  __shared__ float sv[2048];
  __shared__ int scnt[1024];
  int b = blockIdx.x;
  for (int i=threadIdx.x; i<2048; i+=1024) sv[i] = imp[b*2048 + i];
  __syncthreads();
  int i0 = threadIdx.x*2;
  float v0 = sv[i0], v1 = sv[i0+1];
  int r0 = 0, r1 = 0;
  for (int j=0; j<2048; ++j){
    float vj = sv[j];
    r0 += (vj > v0) || (vj == v0 && j < i0);
    r1 += (vj > v1) || (vj == v1 && j < i0+1);
  }
  int f0 = (r0 < KK), f1 = (r1 < KK);
  int c = f0 + f1;
  scnt[threadIdx.x] = c;
  __syncthreads();
  for (int off=1; off<1024; off<<=1){
    int add = (threadIdx.x >= off) ? scnt[threadIdx.x - off] : 0;
    __syncthreads();
    scnt[threadIdx.x] += add;
    __syncthreads();
  }
  int pos = scnt[threadIdx.x] - c;
  if (f0) idxout[b*KK + pos++] = i0;
  if (f1) idxout[b*KK + pos]   = i0+1;
}

// --------------------------------------- gather + BatchNorm + write idx
__global__ __launch_bounds__(256) void final_kernel(const float* __restrict__ rb,
    const int* __restrict__ idx, const float* __restrict__ g, const float* __restrict__ bt,
    const float* __restrict__ mean, const float* __restrict__ var,
    float* __restrict__ out, int KK){
  int row = blockIdx.x*4 + (threadIdx.x>>6);
  int lane = threadIdx.x & 63;
  int total = NBATCH*KK;
  if (row < total){
    int b = row / KK;
    int src = idx[row];
    float4 v  = *(const float4*)(rb + ((size_t)(b*SEQ+src))*DM + lane*4);
    float4 gm = *(const float4*)(mean + lane*4);
    float4 gv = *(const float4*)(var  + lane*4);
    float4 gg = *(const float4*)(g    + lane*4);
    float4 gb = *(const float4*)(bt   + lane*4);
    float4 o;
    o.x = (v.x-gm.x)*rsqrtf(gv.x+1e-3f)*gg.x + gb.x;
    o.y = (v.y-gm.y)*rsqrtf(gv.y+1e-3f)*gg.y + gb.y;
    o.z = (v.z-gm.z)*rsqrtf(gv.z+1e-3f)*gg.z + gb.z;
    o.w = (v.w-gm.w)*rsqrtf(gv.w+1e-3f)*gg.w + gb.w;
    *(float4*)(out + (size_t)row*DM + lane*4) = o;
  }
  int gid = blockIdx.x*256 + threadIdx.x;
  if (gid < total) out[(size_t)total*DM + gid] = (float)idx[gid];
}

// ================================================================== launch
extern "C" void kernel_launch(void* const* d_in, const int* in_sizes, int n_in,
                              void* d_out, int out_size, void* d_ws, size_t ws_size,
                              hipStream_t stream){
  (void)in_sizes; (void)n_in; (void)ws_size;
  const float* x    = (const float*)d_in[0];
  const float* ln1g = (const float*)d_in[1];
  const float* ln1b = (const float*)d_in[2];
  const float* ln2g = (const float*)d_in[3];
  const float* ln2b = (const float*)d_in[4];
  const float* ln3g = (const float*)d_in[5];
  const float* ln3b = (const float*)d_in[6];
  const float* gqw = (const float*)d_in[7];  const float* gqb = (const float*)d_in[8];
  const float* gkw = (const float*)d_in[9];  const float* gkb = (const float*)d_in[10];
  const float* gvw = (const float*)d_in[11]; const float* gvb = (const float*)d_in[12];
  const float* gow = (const float*)d_in[13]; const float* gob = (const float*)d_in[14];
  const float* lqw = (const float*)d_in[15]; const float* lqb = (const float*)d_in[16];
  const float* lkw = (const float*)d_in[17]; const float* lkb = (const float*)d_in[18];
  const float* lvw = (const float*)d_in[19]; const float* lvb = (const float*)d_in[20];
  const float* low = (const float*)d_in[21]; const float* lob = (const float*)d_in[22];
  const float* fw1 = (const float*)d_in[23]; const float* fb1 = (const float*)d_in[24];
  const float* fw2 = (const float*)d_in[25]; const float* fb2 = (const float*)d_in[26];
  const float* resw = (const float*)d_in[27]; const float* resb = (const float*)d_in[28];
  const float* bng = (const float*)d_in[29]; const float* bnb = (const float*)d_in[30];
  const float* bnm = (const float*)d_in[31]; const float* bnv = (const float*)d_in[32];

  float* ws = (float*)d_ws;
  const size_t M1 = 2097152;                 // B*S*D
  float* r1 = ws;
  float* r2 = ws + M1;
  float* r3 = ws + 2*M1;
  unsigned short* nb  = (unsigned short*)(ws + 3*M1);
  unsigned short* qbf = (unsigned short*)(ws + 3*M1 + M1/2);
  unsigned short* kbf = (unsigned short*)(ws + 4*M1);
  unsigned short* vbf = (unsigned short*)(ws + 4*M1 + M1/2);
  unsigned short* vtb = (unsigned short*)(ws + 5*M1);
  unsigned short* obf = (unsigned short*)(ws + 5*M1 + M1/2);
  unsigned short* h1  = (unsigned short*)(ws + 6*M1);   // 8192x1024 bf16 = [6M1, 8M1)
  unsigned short* wT  = (unsigned short*)(ws + 8*M1);   // transposed weights
  unsigned short* wgq = wT;            unsigned short* wgk = wT + 65536;
  unsigned short* wgv = wT + 131072;   unsigned short* wgo = wT + 196608;
  unsigned short* wlq = wT + 262144;   unsigned short* wlk = wT + 327680;
  unsigned short* wlv = wT + 393216;   unsigned short* wlo = wT + 458752;
  unsigned short* wre = wT + 524288;
  unsigned short* wf1 = wT + 589824;   // 256x1024 -> [1024][256]
  unsigned short* wf2 = wT + 851968;   // 1024x256 -> [256][1024]
  unsigned short* xbf = (unsigned short*)(ws + 9*M1);
  float* Ms   = ws + 10*M1;
  float* Ls   = ws + 10*M1 + 65536;
  float* colG = ws + 10*M1 + 131072;
  float* colL = ws + 10*M1 + 196608;
  float* impb = ws + 10*M1 + 262144;
  int*   idxb = (int*)(ws + 10*M1 + 270336);

  int KK = out_size / (NBATCH*(DM+1));
  float* out = (float*)d_out;

  // ---- weight prep (input-only deps)
  wtrans_kernel<<<32,256,0,stream>>>(gqw, wgq, 256,256);
  wtrans_kernel<<<32,256,0,stream>>>(gkw, wgk, 256,256);
  wtrans_kernel<<<32,256,0,stream>>>(gvw, wgv, 256,256);
  wtrans_kernel<<<32,256,0,stream>>>(gow, wgo, 256,256);
  wtrans_kernel<<<32,256,0,stream>>>(lqw, wlq, 256,256);
  wtrans_kernel<<<32,256,0,stream>>>(lkw, wlk, 256,256);
  wtrans_kernel<<<32,256,0,stream>>>(lvw, wlv, 256,256);
  wtrans_kernel<<<32,256,0,stream>>>(low, wlo, 256,256);
  wtrans_kernel<<<32,256,0,stream>>>(resw, wre, 256,256);
  wtrans_kernel<<<128,256,0,stream>>>(fw1, wf1, 256,1024);
  wtrans_kernel<<<128,256,0,stream>>>(fw2, wf2, 1024,256);
  cvt_kernel<<<2048,256,0,stream>>>(x, xbf, (int)(M1/4));

  // ---- block 1: global attention
  ln_kernel<<<2048,256,0,stream>>>(x, ln1g, ln1b, nb);
  gemm_bf16<<<256,256,0,stream>>>(nb, wgq, gqb, nullptr, qbf, 8192,256,256, 2, SCALE);
  gemm_bf16<<<256,256,0,stream>>>(nb, wgk, gkb, nullptr, kbf, 8192,256,256, 2, 1.0f);
  gemm_bf16<<<256,256,0,stream>>>(nb, wgv, gvb, nullptr, vbf, 8192,256,256, 2, 1.0f);
  vtrans_kernel<<<512,256,0,stream>>>(vbf, vtb);
  flash_kernel<<<1024,256,0,stream>>>(qbf, kbf, vtb, obf, Ms, Ls);
  colsum_kernel<<<1024,256,0,stream>>>(qbf, kbf, Ms, Ls, colG);
  gemm_bf16<<<256,256,0,stream>>>(obf, wgo, gob, x, r1, 8192,256,256, 0, 1.0f);

  // ---- block 2: local attention
  ln_kernel<<<2048,256,0,stream>>>(r1, ln2g, ln2b, nb);
  gemm_bf16<<<256,256,0,stream>>>(nb, wlq, lqb, nullptr, qbf, 8192,256,256, 2, SCALE);
  gemm_bf16<<<256,256,0,stream>>>(nb, wlk, lkb, nullptr, kbf, 8192,256,256, 2, 1.0f);
  gemm_bf16<<<256,256,0,stream>>>(nb, wlv, lvb, nullptr, vbf, 8192,256,256, 2, 1.0f);
  vtrans_kernel<<<512,256,0,stream>>>(vbf, vtb);
  flash_kernel<<<1024,256,0,stream>>>(qbf, kbf, vtb, obf, Ms, Ls);
  colsum_kernel<<<1024,256,0,stream>>>(qbf, kbf, Ms, Ls, colL);
  gemm_bf16<<<256,256,0,stream>>>(obf, wlo, lob, r1, r2, 8192,256,256, 0, 1.0f);

  // ---- FFN
  ln_kernel<<<2048,256,0,stream>>>(r2, ln3g, ln3b, nb);
  gemm_bf16<<<1024,256,0,stream>>>(nb, wf1, fb1, nullptr, h1, 8192,1024,256, 1|2, 1.0f);
  gemm_bf16<<<256,256,0,stream>>>(h1, wf2, fb2, r2, r3, 8192,256,1024, 0, 1.0f);
  gemm_bf16<<<256,256,0,stream>>>(xbf, wre, resb, r3, r3, 8192,256,256, 0, 1.0f);

  // ---- importance -> top-K -> gather + BN + idx
  imp_kernel<<<32,256,0,stream>>>(colG, colL, impb);
  topk_kernel<<<NBATCH,1024,0,stream>>>(impb, KK, idxb);
  int total = NBATCH*KK;
  final_kernel<<<(total+3)/4,256,0,stream>>>(r3, idxb, bng, bnb, bnm, bnv, out, KK);
}

// Round 4
// 560.379 us; speedup vs baseline: 4.0566x; 1.2179x over previous
//
#include <hip/hip_runtime.h>

#define SEQ 2048
#define DM 256
#define NH 8
#define DKH 32
#define NBATCH 4
#define SCALE 0.17677669529663687f

typedef __attribute__((ext_vector_type(8))) __bf16 bf16x8;
typedef __attribute__((ext_vector_type(4))) float floatx4;
typedef __attribute__((ext_vector_type(8))) short short8v;

__device__ inline unsigned short f2bf(float x){
  union { float f; unsigned u; } v; v.f = x;
  unsigned r = v.u + 0x7FFFu + ((v.u >> 16) & 1u);
  return (unsigned short)(r >> 16);
}

// ------------------------------------------- LayerNorm fp32 in -> bf16 out
__global__ __launch_bounds__(256) void ln_kernel(const float* __restrict__ X,
    const float* __restrict__ G, const float* __restrict__ Bv,
    unsigned short* __restrict__ Y){
  int row = blockIdx.x*4 + (threadIdx.x>>6);
  int lane = threadIdx.x & 63;
  const float4 v = *(const float4*)(X + (size_t)row*DM + lane*4);
  float s = v.x+v.y+v.z+v.w;
  #pragma unroll
  for (int off=32; off; off>>=1) s += __shfl_xor(s, off, 64);
  float mean = s * (1.0f/DM);
  float dx=v.x-mean, dy=v.y-mean, dz=v.z-mean, dw=v.w-mean;
  float ss = dx*dx+dy*dy+dz*dz+dw*dw;
  #pragma unroll
  for (int off=32; off; off>>=1) ss += __shfl_xor(ss, off, 64);
  float r = rsqrtf(ss*(1.0f/DM) + 1e-6f);
  const float4 g = *(const float4*)(G + lane*4);
  const float4 b = *(const float4*)(Bv + lane*4);
  ushort4 o;
  o.x = f2bf(dx*r*g.x + b.x);
  o.y = f2bf(dy*r*g.y + b.y);
  o.z = f2bf(dz*r*g.z + b.z);
  o.w = f2bf(dw*r*g.w + b.w);
  *(ushort4*)(Y + (size_t)row*DM + lane*4) = o;
}

// ----------------------------------------------- fp32 -> bf16 plain convert
__global__ __launch_bounds__(256) void cvt_kernel(const float* __restrict__ src,
    unsigned short* __restrict__ dst, int n4){
  int i = blockIdx.x*256 + threadIdx.x;
  if (i >= n4) return;
  float4 v = ((const float4*)src)[i];
  ushort4 o;
  o.x = f2bf(v.x); o.y = f2bf(v.y); o.z = f2bf(v.z); o.w = f2bf(v.w);
  ((ushort4*)dst)[i] = o;
}

// ------------- batched weight transpose+convert: fp32 [K][N] -> bf16 [N][K]
struct WtArgs {
  const float* src[11];
  unsigned short* dst[11];
  int K[11], N[11];
  int blk0[12];
};
__global__ __launch_bounds__(256) void wtrans_all(WtArgs a){
  __shared__ unsigned short sT[64][40];      // [n][k] tile
  int wi = 0;
  while (blockIdx.x >= (unsigned)a.blk0[wi+1]) ++wi;
  int blk = blockIdx.x - a.blk0[wi];
  const float* W = a.src[wi];
  unsigned short* Wt = a.dst[wi];
  int K = a.K[wi], N = a.N[wi];
  int nbk = N >> 6;
  int bx = blk % nbk, by = blk / nbk;
  int k0 = by << 5, n0 = bx << 6;
  int tid = threadIdx.x;
  int r = tid >> 3, cs = (tid & 7) << 3;
  const float* ip = W + (size_t)(k0+r)*N + n0 + cs;
  float4 av = *(const float4*)ip;
  float4 bq = *(const float4*)(ip+4);
  sT[cs+0][r]=f2bf(av.x); sT[cs+1][r]=f2bf(av.y); sT[cs+2][r]=f2bf(av.z); sT[cs+3][r]=f2bf(av.w);
  sT[cs+4][r]=f2bf(bq.x); sT[cs+5][r]=f2bf(bq.y); sT[cs+6][r]=f2bf(bq.z); sT[cs+7][r]=f2bf(bq.w);
  __syncthreads();
  int n = tid >> 2, kc = (tid & 3) << 3;
  *(short8v*)(Wt + (size_t)(n0+n)*K + k0 + kc) = *(const short8v*)(&sT[n][kc]);
}

// ------------------- V bf16 [b*S][256] -> Vt bf16 [(b*8+h)*32+d][S]
__global__ __launch_bounds__(256) void vtrans_kernel(const unsigned short* __restrict__ V,
    unsigned short* __restrict__ Vt){
  __shared__ unsigned short sT[32][136];
  int kt = blockIdx.x & 15, bh = blockIdx.x >> 4;
  int h = bh & 7, b = bh >> 3;
  int t0 = kt << 7;
  int tid = threadIdx.x;
  int key = tid >> 1, half = (tid & 1) << 4;
  const unsigned short* vp = V + (size_t)(b*SEQ + t0 + key)*DM + h*DKH + half;
  union {short8v v; unsigned short u[8];} ua, ub;
  ua.v = *(const short8v*)vp;
  ub.v = *(const short8v*)(vp+8);
  #pragma unroll
  for (int j=0;j<8;++j){ sT[half+j][key] = ua.u[j]; sT[half+8+j][key] = ub.u[j]; }
  __syncthreads();
  int d = tid >> 3, kc = (tid & 7) << 4;
  unsigned short* op = Vt + (size_t)(bh*DKH + d)*SEQ + t0 + kc;
  *(short8v*)op     = *(const short8v*)(&sT[d][kc]);
  *(short8v*)(op+8) = *(const short8v*)(&sT[d][kc+8]);
}

// ---------------------------------------------------------- bf16 MFMA GEMM
// C[M,N] = A[M,K] @ Bt[N,K]^T + bias (+Res fp32) (opt relu) (opt *outscale)
// flags: 1 = relu, 2 = bf16 output
__global__ __launch_bounds__(256) void gemm_bf16(const unsigned short* __restrict__ A,
    const unsigned short* __restrict__ Bt, const float* __restrict__ bias,
    const float* __restrict__ Res, void* __restrict__ Cout,
    int M, int N, int K, int flags, float outscale){
  __shared__ unsigned short sA[8192];
  __shared__ unsigned short sB[4096];
  int nbk = N >> 6;
  int bx = blockIdx.x % nbk, by = blockIdx.x / nbk;
  int m0 = by << 7, n0 = bx << 6;
  int tid = threadIdx.x, w = tid >> 6, lane = tid & 63;
  int m16 = lane & 15, quad = lane >> 4;
  int wr = w & 1, wc = w >> 1;
  floatx4 acc[4][2];
  #pragma unroll
  for (int i=0;i<4;++i){ acc[i][0]=(floatx4){0,0,0,0}; acc[i][1]=(floatx4){0,0,0,0}; }
  for (int k0=0; k0<K; k0+=64){
    __syncthreads();
    #pragma unroll
    for (int i=0;i<4;++i){
      int c = tid + i*256;
      int l = c & 63, kk = (c>>6)&1, mt = c>>7;
      int row = m0 + mt*16 + (l&15);
      int col = k0 + kk*32 + ((l>>4)<<3);
      *(short8v*)(sA + c*8) = *(const short8v*)(A + (size_t)row*K + col);
    }
    #pragma unroll
    for (int i=0;i<2;++i){
      int c = tid + i*256;
      int l = c & 63, kk = (c>>6)&1, nt = c>>7;
      int row = n0 + nt*16 + (l&15);
      int col = k0 + kk*32 + ((l>>4)<<3);
      *(short8v*)(sB + c*8) = *(const short8v*)(Bt + (size_t)row*K + col);
    }
    __syncthreads();
    #pragma unroll
    for (int kk=0;kk<2;++kk){
      bf16x8 bf0 = *(const bf16x8*)(sB + (((wc*2+0)*2+kk)*64 + lane)*8);
      bf16x8 bf1 = *(const bf16x8*)(sB + (((wc*2+1)*2+kk)*64 + lane)*8);
      #pragma unroll
      for (int mt=0;mt<4;++mt){
        bf16x8 af = *(const bf16x8*)(sA + (((wr*4+mt)*2+kk)*64 + lane)*8);
        acc[mt][0] = __builtin_amdgcn_mfma_f32_16x16x32_bf16(af, bf0, acc[mt][0], 0,0,0);
        acc[mt][1] = __builtin_amdgcn_mfma_f32_16x16x32_bf16(af, bf1, acc[mt][1], 0,0,0);
      }
    }
  }
  float b0 = bias ? bias[n0 + wc*32 + m16]      : 0.0f;
  float b1 = bias ? bias[n0 + wc*32 + 16 + m16] : 0.0f;
  #pragma unroll
  for (int mt=0;mt<4;++mt){
    #pragma unroll
    for (int r=0;r<4;++r){
      size_t row = (size_t)m0 + wr*64 + mt*16 + quad*4 + r;
      int col0 = n0 + wc*32 + m16, col1 = col0 + 16;
      float v0 = acc[mt][0][r] + b0, v1 = acc[mt][1][r] + b1;
      if (Res){ v0 += Res[row*N + col0]; v1 += Res[row*N + col1]; }
      if (flags & 1){ v0 = fmaxf(v0, 0.0f); v1 = fmaxf(v1, 0.0f); }
      v0 *= outscale; v1 *= outscale;
      if (flags & 2){
        unsigned short* C = (unsigned short*)Cout;
        C[row*N + col0] = f2bf(v0); C[row*N + col1] = f2bf(v1);
      } else {
        float* C = (float*)Cout;
        C[row*N + col0] = v0; C[row*N + col1] = v1;
      }
    }
  }
}

// ------------------------------------------------ fused flash MFMA attention
__global__ __launch_bounds__(256) void flash_kernel(
    const unsigned short* __restrict__ Qb, const unsigned short* __restrict__ Kb,
    const unsigned short* __restrict__ Vt, unsigned short* __restrict__ Obf,
    float* __restrict__ Mout, float* __restrict__ Lout){
  __shared__ unsigned short sK[4096];
  __shared__ unsigned short sV[4096];
  __shared__ unsigned short sP[4*2048];
  int qb = blockIdx.x & 31, bh = blockIdx.x >> 5;
  int h = bh & 7, b = bh >> 3;
  int tid = threadIdx.x, w = tid >> 6, lane = tid & 63;
  int m16 = lane & 15, quad = lane >> 4;
  int qrow0 = qb*64 + w*16;
  bf16x8 qfrag = *(const bf16x8*)(Qb + (size_t)(b*SEQ + qrow0 + m16)*DM + h*DKH + quad*8);
  floatx4 o0 = {0,0,0,0}, o1 = {0,0,0,0};
  float ms[4], ls[4];
  #pragma unroll
  for (int r=0;r<4;++r){ ms[r] = -__builtin_inff(); ls[r] = 0.0f; }
  unsigned short* sPw = sP + w*2048;
  int wA = quad*4, wB = (m16>>3)*16, wC = m16&7;
  int wbase = (wA + wB)*8 + wC;

  for (int t0=0; t0<SEQ; t0+=128){
    __syncthreads();
    #pragma unroll
    for (int i=0;i<2;++i){
      int c = tid + i*256;
      int l = c & 63;
      {
        int kt = c >> 6;
        int key = t0 + kt*16 + (l&15);
        int dc = (l>>4)<<3;
        *(short8v*)(sK + c*8) = *(const short8v*)(Kb + (size_t)(b*SEQ+key)*DM + h*DKH + dc);
      }
      {
        int nt = (c>>6)&1, ks = c>>7;
        int d = nt*16 + (l&15);
        int ko = ks*32 + ((l>>4)<<3);
        *(short8v*)(sV + c*8) = *(const short8v*)(Vt + (size_t)(bh*DKH + d)*SEQ + t0 + ko);
      }
    }
    __syncthreads();
    floatx4 z = {0,0,0,0};
    floatx4 s[8];
    #pragma unroll
    for (int kt=0;kt<8;++kt){
      bf16x8 kf = *(const bf16x8*)(sK + (kt*64+lane)*8);
      s[kt] = __builtin_amdgcn_mfma_f32_16x16x32_bf16(qfrag, kf, z, 0,0,0);
    }
    #pragma unroll
    for (int r=0;r<4;++r){
      float mx = s[0][r];
      #pragma unroll
      for (int kt=1;kt<8;++kt) mx = fmaxf(mx, s[kt][r]);
      mx = fmaxf(mx, __shfl_xor(mx, 1, 64));
      mx = fmaxf(mx, __shfl_xor(mx, 2, 64));
      mx = fmaxf(mx, __shfl_xor(mx, 4, 64));
      mx = fmaxf(mx, __shfl_xor(mx, 8, 64));
      float mn = fmaxf(ms[r], mx);
      float a  = __expf(ms[r] - mn);
      float p[8]; float rs = 0.0f;
      #pragma unroll
      for (int kt=0;kt<8;++kt){ p[kt] = __expf(s[kt][r] - mn); rs += p[kt]; }
      rs += __shfl_xor(rs, 1, 64);
      rs += __shfl_xor(rs, 2, 64);
      rs += __shfl_xor(rs, 4, 64);
      rs += __shfl_xor(rs, 8, 64);
      ls[r] = ls[r]*a + rs;
      ms[r] = mn;
      o0[r] *= a; o1[r] *= a;
      #pragma unroll
      for (int kt=0;kt<8;++kt) sPw[kt*256 + wbase + r*8] = f2bf(p[kt]);
    }
    #pragma unroll
    for (int ks=0;ks<4;++ks){
      bf16x8 pf  = *(const bf16x8*)(sPw + (ks*64+lane)*8);
      bf16x8 vf0 = *(const bf16x8*)(sV + ((ks*2+0)*64+lane)*8);
      bf16x8 vf1 = *(const bf16x8*)(sV + ((ks*2+1)*64+lane)*8);
      o0 = __builtin_amdgcn_mfma_f32_16x16x32_bf16(pf, vf0, o0, 0,0,0);
      o1 = __builtin_amdgcn_mfma_f32_16x16x32_bf16(pf, vf1, o1, 0,0,0);
    }
  }
  #pragma unroll
  for (int r=0;r<4;++r){
    float inv = 1.0f / ls[r];
    int q = qrow0 + quad*4 + r;
    size_t base = (size_t)(b*SEQ + q)*DM + h*DKH;
    Obf[base + m16]      = f2bf(o0[r]*inv);
    Obf[base + 16 + m16] = f2bf(o1[r]*inv);
    if (m16 == 0){
      Mout[(size_t)bh*SEQ + q] = ms[r];
      Lout[(size_t)bh*SEQ + q] = inv;
    }
  }
}

// --------------------- column sums of softmax weights (recompute S via MFMA)
__global__ __launch_bounds__(256) void colsum_kernel(
    const unsigned short* __restrict__ Qb, const unsigned short* __restrict__ Kb,
    const float* __restrict__ Mv, const float* __restrict__ Lv,
    float* __restrict__ col){
  __shared__ unsigned short sQ[2048];
  __shared__ float sM[64], sL[64];
  int kc = blockIdx.x & 31, bh = blockIdx.x >> 5;
  int h = bh & 7, b = bh >> 3;
  int tid = threadIdx.x, w = tid >> 6, lane = tid & 63;
  int m16 = lane & 15, quad = lane >> 4;
  int key = kc*64 + w*16 + m16;
  bf16x8 kfrag = *(const bf16x8*)(Kb + (size_t)(b*SEQ+key)*DM + h*DKH + quad*8);
  float acc[4] = {0,0,0,0};
  for (int q0=0; q0<SEQ; q0+=64){
    __syncthreads();
    {
      int c = tid;
      int l = c & 63, qt = c >> 6;
      int q = q0 + qt*16 + (l&15);
      int dc = (l>>4)<<3;
      *(short8v*)(sQ + c*8) = *(const short8v*)(Qb + (size_t)(b*SEQ+q)*DM + h*DKH + dc);
      if (tid < 64) sM[tid] = Mv[(size_t)bh*SEQ + q0 + tid];
      else if (tid < 128) sL[tid-64] = Lv[(size_t)bh*SEQ + q0 + tid - 64];
    }
    __syncthreads();
    floatx4 z = {0,0,0,0};
    #pragma unroll
    for (int qt=0;qt<4;++qt){
      bf16x8 qf = *(const bf16x8*)(sQ + (qt*64+lane)*8);
      floatx4 t = __builtin_amdgcn_mfma_f32_16x16x32_bf16(kfrag, qf, z, 0,0,0);
      float mq = sM[qt*16+m16], lq = sL[qt*16+m16];
      #pragma unroll
      for (int r=0;r<4;++r) acc[r] += __expf(t[r]-mq)*lq;
    }
  }
  #pragma unroll
  for (int r=0;r<4;++r){
    float v = acc[r];
    v += __shfl_xor(v, 1, 64);
    v += __shfl_xor(v, 2, 64);
    v += __shfl_xor(v, 4, 64);
    v += __shfl_xor(v, 8, 64);
    if (m16 == 0) col[(size_t)bh*SEQ + kc*64 + w*16 + quad*4 + r] = v;
  }
}

// ------------------------------------- importance = 0.7*G + 0.3*L (fp64 acc)
__global__ __launch_bounds__(256) void imp_kernel(const float* __restrict__ colG,
    const float* __restrict__ colL, float* __restrict__ imp){
  int i = blockIdx.x*256 + threadIdx.x;
  int b = i >> 11, t = i & 2047;
  double sg = 0.0, sl = 0.0;
  for (int h=0; h<8; ++h){
    sg += (double)colG[(size_t)(b*8+h)*SEQ + t];
    sl += (double)colL[(size_t)(b*8+h)*SEQ + t];
  }
  imp[i] = (float)(0.7*sg + 0.3*sl);
}

// --------------------- rank of each element (desc value, asc index tie-break)
// 8 blocks per batch, 256 elements/block, imp row staged in LDS.
__global__ __launch_bounds__(256) void rank_kernel(const float* __restrict__ imp,
    int* __restrict__ rank){
  __shared__ float sv[2048];
  int b = blockIdx.x >> 3;
  int chunk = blockIdx.x & 7;
  for (int i=threadIdx.x; i<2048; i+=256) sv[i] = imp[b*2048 + i];
  __syncthreads();
  int i = chunk*256 + threadIdx.x;
  float v = sv[i];
  int r = 0;
  for (int j=0; j<2048; j+=4){
    float4 vj = *(const float4*)&sv[j];
    r += (vj.x > v) || (vj.x == v && (j+0) < i);
    r += (vj.y > v) || (vj.y == v && (j+1) < i);
    r += (vj.z > v) || (vj.z == v && (j+2) < i);
    r += (vj.w > v) || (vj.w == v && (j+3) < i);
  }
  rank[b*2048 + i] = r;
}

// --------------------- compact indices with rank < KK (ascending order)
__global__ __launch_bounds__(256) void compact_kernel(const int* __restrict__ rank,
    int KK, int* __restrict__ idxout){
  __shared__ int swave[4];
  int b = blockIdx.x;
  int tid = threadIdx.x, w = tid >> 6, lane = tid & 63;
  int base = tid*8;
  int f[8]; int c = 0;
  #pragma unroll
  for (int j=0;j<8;++j){ f[j] = (rank[b*2048 + base + j] < KK) ? 1 : 0; c += f[j]; }
  int pref = c;
  #pragma unroll
  for (int off=1; off<64; off<<=1){
    int t = __shfl_up(pref, off, 64);
    if (lane >= off) pref += t;
  }
  if (lane == 63) swave[w] = pref;
  __syncthreads();
  int wbase = 0;
  for (int k=0;k<w;++k) wbase += swave[k];
  int pos = wbase + pref - c;
  #pragma unroll
  for (int j=0;j<8;++j){
    if (f[j]) idxout[b*KK + pos++] = base + j;
  }
}

// --------------------------------------- gather + BatchNorm + write idx
__global__ __launch_bounds__(256) void final_kernel(const float* __restrict__ rb,
    const int* __restrict__ idx, const float* __restrict__ g, const float* __restrict__ bt,
    const float* __restrict__ mean, const float* __restrict__ var,
    float* __restrict__ out, int KK){
  int row = blockIdx.x*4 + (threadIdx.x>>6);
  int lane = threadIdx.x & 63;
  int total = NBATCH*KK;
  if (row < total){
    int b = row / KK;
    int src = idx[row];
    float4 v  = *(const float4*)(rb + ((size_t)(b*SEQ+src))*DM + lane*4);
    float4 gm = *(const float4*)(mean + lane*4);
    float4 gv = *(const float4*)(var  + lane*4);
    float4 gg = *(const float4*)(g    + lane*4);
    float4 gb = *(const float4*)(bt   + lane*4);
    float4 o;
    o.x = (v.x-gm.x)*rsqrtf(gv.x+1e-3f)*gg.x + gb.x;
    o.y = (v.y-gm.y)*rsqrtf(gv.y+1e-3f)*gg.y + gb.y;
    o.z = (v.z-gm.z)*rsqrtf(gv.z+1e-3f)*gg.z + gb.z;
    o.w = (v.w-gm.w)*rsqrtf(gv.w+1e-3f)*gg.w + gb.w;
    *(float4*)(out + (size_t)row*DM + lane*4) = o;
  }
  int gid = blockIdx.x*256 + threadIdx.x;
  if (gid < total) out[(size_t)total*DM + gid] = (float)idx[gid];
}

// ================================================================== launch
extern "C" void kernel_launch(void* const* d_in, const int* in_sizes, int n_in,
                              void* d_out, int out_size, void* d_ws, size_t ws_size,
                              hipStream_t stream){
  (void)in_sizes; (void)n_in; (void)ws_size;
  const float* x    = (const float*)d_in[0];
  const float* ln1g = (const float*)d_in[1];
  const float* ln1b = (const float*)d_in[2];
  const float* ln2g = (const float*)d_in[3];
  const float* ln2b = (const float*)d_in[4];
  const float* ln3g = (const float*)d_in[5];
  const float* ln3b = (const float*)d_in[6];
  const float* gqw = (const float*)d_in[7];  const float* gqb = (const float*)d_in[8];
  const float* gkw = (const float*)d_in[9];  const float* gkb = (const float*)d_in[10];
  const float* gvw = (const float*)d_in[11]; const float* gvb = (const float*)d_in[12];
  const float* gow = (const float*)d_in[13]; const float* gob = (const float*)d_in[14];
  const float* lqw = (const float*)d_in[15]; const float* lqb = (const float*)d_in[16];
  const float* lkw = (const float*)d_in[17]; const float* lkb = (const float*)d_in[18];
  const float* lvw = (const float*)d_in[19]; const float* lvb = (const float*)d_in[20];
  const float* low = (const float*)d_in[21]; const float* lob = (const float*)d_in[22];
  const float* fw1 = (const float*)d_in[23]; const float* fb1 = (const float*)d_in[24];
  const float* fw2 = (const float*)d_in[25]; const float* fb2 = (const float*)d_in[26];
  const float* resw = (const float*)d_in[27]; const float* resb = (const float*)d_in[28];
  const float* bng = (const float*)d_in[29]; const float* bnb = (const float*)d_in[30];
  const float* bnm = (const float*)d_in[31]; const float* bnv = (const float*)d_in[32];

  float* ws = (float*)d_ws;
  const size_t M1 = 2097152;                 // B*S*D
  float* r1 = ws;
  float* r2 = ws + M1;
  float* r3 = ws + 2*M1;
  unsigned short* nb  = (unsigned short*)(ws + 3*M1);
  unsigned short* qbf = (unsigned short*)(ws + 3*M1 + M1/2);
  unsigned short* kbf = (unsigned short*)(ws + 4*M1);
  unsigned short* vbf = (unsigned short*)(ws + 4*M1 + M1/2);
  unsigned short* vtb = (unsigned short*)(ws + 5*M1);
  unsigned short* obf = (unsigned short*)(ws + 5*M1 + M1/2);
  unsigned short* h1  = (unsigned short*)(ws + 6*M1);   // 8192x1024 bf16
  unsigned short* wT  = (unsigned short*)(ws + 8*M1);
  unsigned short* wgq = wT;            unsigned short* wgk = wT + 65536;
  unsigned short* wgv = wT + 131072;   unsigned short* wgo = wT + 196608;
  unsigned short* wlq = wT + 262144;   unsigned short* wlk = wT + 327680;
  unsigned short* wlv = wT + 393216;   unsigned short* wlo = wT + 458752;
  unsigned short* wre = wT + 524288;
  unsigned short* wf1 = wT + 589824;
  unsigned short* wf2 = wT + 851968;
  unsigned short* xbf = (unsigned short*)(ws + 9*M1);
  float* Ms   = ws + 10*M1;
  float* Ls   = ws + 10*M1 + 65536;
  float* colG = ws + 10*M1 + 131072;
  float* colL = ws + 10*M1 + 196608;
  float* impb = ws + 10*M1 + 262144;
  int*   rnk  = (int*)(ws + 10*M1 + 270336);
  int*   idxb = (int*)(ws + 10*M1 + 278528);

  int KK = out_size / (NBATCH*(DM+1));
  float* out = (float*)d_out;

  // ---- weight prep: one batched launch (11 transposes)
  WtArgs wa;
  const float* srcs[11] = {gqw,gkw,gvw,gow,lqw,lkw,lvw,low,resw,fw1,fw2};
  unsigned short* dsts[11] = {wgq,wgk,wgv,wgo,wlq,wlk,wlv,wlo,wre,wf1,wf2};
  int Ks[11] = {256,256,256,256,256,256,256,256,256,256,1024};
  int Ns[11] = {256,256,256,256,256,256,256,256,256,1024,256};
  int acc = 0;
  for (int i=0;i<11;++i){
    wa.src[i]=srcs[i]; wa.dst[i]=dsts[i]; wa.K[i]=Ks[i]; wa.N[i]=Ns[i];
    wa.blk0[i]=acc; acc += (Ks[i]>>5)*(Ns[i]>>6);
  }
  wa.blk0[11]=acc;
  wtrans_all<<<acc,256,0,stream>>>(wa);
  cvt_kernel<<<2048,256,0,stream>>>(x, xbf, (int)(M1/4));

  // ---- block 1: global attention
  ln_kernel<<<2048,256,0,stream>>>(x, ln1g, ln1b, nb);
  gemm_bf16<<<256,256,0,stream>>>(nb, wgq, gqb, nullptr, qbf, 8192,256,256, 2, SCALE);
  gemm_bf16<<<256,256,0,stream>>>(nb, wgk, gkb, nullptr, kbf, 8192,256,256, 2, 1.0f);
  gemm_bf16<<<256,256,0,stream>>>(nb, wgv, gvb, nullptr, vbf, 8192,256,256, 2, 1.0f);
  vtrans_kernel<<<512,256,0,stream>>>(vbf, vtb);
  flash_kernel<<<1024,256,0,stream>>>(qbf, kbf, vtb, obf, Ms, Ls);
  colsum_kernel<<<1024,256,0,stream>>>(qbf, kbf, Ms, Ls, colG);
  gemm_bf16<<<256,256,0,stream>>>(obf, wgo, gob, x, r1, 8192,256,256, 0, 1.0f);

  // ---- block 2: local attention
  ln_kernel<<<2048,256,0,stream>>>(r1, ln2g, ln2b, nb);
  gemm_bf16<<<256,256,0,stream>>>(nb, wlq, lqb, nullptr, qbf, 8192,256,256, 2, SCALE);
  gemm_bf16<<<256,256,0,stream>>>(nb, wlk, lkb, nullptr, kbf, 8192,256,256, 2, 1.0f);
  gemm_bf16<<<256,256,0,stream>>>(nb, wlv, lvb, nullptr, vbf, 8192,256,256, 2, 1.0f);
  vtrans_kernel<<<512,256,0,stream>>>(vbf, vtb);
  flash_kernel<<<1024,256,0,stream>>>(qbf, kbf, vtb, obf, Ms, Ls);
  colsum_kernel<<<1024,256,0,stream>>>(qbf, kbf, Ms, Ls, colL);
  gemm_bf16<<<256,256,0,stream>>>(obf, wlo, lob, r1, r2, 8192,256,256, 0, 1.0f);

  // ---- FFN
  ln_kernel<<<2048,256,0,stream>>>(r2, ln3g, ln3b, nb);
  gemm_bf16<<<1024,256,0,stream>>>(nb, wf1, fb1, nullptr, h1, 8192,1024,256, 1|2, 1.0f);
  gemm_bf16<<<256,256,0,stream>>>(h1, wf2, fb2, r2, r3, 8192,256,1024, 0, 1.0f);
  gemm_bf16<<<256,256,0,stream>>>(xbf, wre, resb, r3, r3, 8192,256,256, 0, 1.0f);

  // ---- importance -> rank -> compact -> gather + BN + idx
  imp_kernel<<<32,256,0,stream>>>(colG, colL, impb);
  rank_kernel<<<32,256,0,stream>>>(impb, rnk);
  compact_kernel<<<NBATCH,256,0,stream>>>(rnk, KK, idxb);
  int total = NBATCH*KK;
  final_kernel<<<(total+3)/4,256,0,stream>>>(r3, idxb, bng, bnb, bnm, bnv, out, KK);
}

// Round 5
// 515.902 us; speedup vs baseline: 4.4063x; 1.0862x over previous
//
#include <hip/hip_runtime.h>

#define SEQ 2048
#define DM 256
#define NH 8
#define DKH 32
#define NBATCH 4
#define SCALE 0.17677669529663687f
#define QSCALE (0.17677669529663687f * 1.4426950408889634f)   // fold log2(e): p = exp2(s)

typedef __attribute__((ext_vector_type(8))) __bf16 bf16x8;
typedef __attribute__((ext_vector_type(4))) float floatx4;
typedef __attribute__((ext_vector_type(8))) short short8v;

__device__ inline unsigned short f2bf(float x){
  union { float f; unsigned u; } v; v.f = x;
  unsigned r = v.u + 0x7FFFu + ((v.u >> 16) & 1u);
  return (unsigned short)(r >> 16);
}

// ------------------------------------------- LayerNorm fp32 in -> bf16 out
__global__ __launch_bounds__(256) void ln_kernel(const float* __restrict__ X,
    const float* __restrict__ G, const float* __restrict__ Bv,
    unsigned short* __restrict__ Y){
  int row = blockIdx.x*4 + (threadIdx.x>>6);
  int lane = threadIdx.x & 63;
  const float4 v = *(const float4*)(X + (size_t)row*DM + lane*4);
  float s = v.x+v.y+v.z+v.w;
  #pragma unroll
  for (int off=32; off; off>>=1) s += __shfl_xor(s, off, 64);
  float mean = s * (1.0f/DM);
  float dx=v.x-mean, dy=v.y-mean, dz=v.z-mean, dw=v.w-mean;
  float ss = dx*dx+dy*dy+dz*dz+dw*dw;
  #pragma unroll
  for (int off=32; off; off>>=1) ss += __shfl_xor(ss, off, 64);
  float r = rsqrtf(ss*(1.0f/DM) + 1e-6f);
  const float4 g = *(const float4*)(G + lane*4);
  const float4 b = *(const float4*)(Bv + lane*4);
  ushort4 o;
  o.x = f2bf(dx*r*g.x + b.x);
  o.y = f2bf(dy*r*g.y + b.y);
  o.z = f2bf(dz*r*g.z + b.z);
  o.w = f2bf(dw*r*g.w + b.w);
  *(ushort4*)(Y + (size_t)row*DM + lane*4) = o;
}

// ----------------------------------------------- fp32 -> bf16 plain convert
__global__ __launch_bounds__(256) void cvt_kernel(const float* __restrict__ src,
    unsigned short* __restrict__ dst, int n4){
  int i = blockIdx.x*256 + threadIdx.x;
  if (i >= n4) return;
  float4 v = ((const float4*)src)[i];
  ushort4 o;
  o.x = f2bf(v.x); o.y = f2bf(v.y); o.z = f2bf(v.z); o.w = f2bf(v.w);
  ((ushort4*)dst)[i] = o;
}

// ------------- batched weight transpose+convert: fp32 [K][N] -> bf16 [N][K]
struct WtArgs {
  const float* src[11];
  unsigned short* dst[11];
  int K[11], N[11];
  int blk0[12];
};
__global__ __launch_bounds__(256) void wtrans_all(WtArgs a){
  __shared__ unsigned short sT[64][40];
  int wi = 0;
  while (blockIdx.x >= (unsigned)a.blk0[wi+1]) ++wi;
  int blk = blockIdx.x - a.blk0[wi];
  const float* W = a.src[wi];
  unsigned short* Wt = a.dst[wi];
  int K = a.K[wi], N = a.N[wi];
  int nbk = N >> 6;
  int bx = blk % nbk, by = blk / nbk;
  int k0 = by << 5, n0 = bx << 6;
  int tid = threadIdx.x;
  int r = tid >> 3, cs = (tid & 7) << 3;
  const float* ip = W + (size_t)(k0+r)*N + n0 + cs;
  float4 av = *(const float4*)ip;
  float4 bq = *(const float4*)(ip+4);
  sT[cs+0][r]=f2bf(av.x); sT[cs+1][r]=f2bf(av.y); sT[cs+2][r]=f2bf(av.z); sT[cs+3][r]=f2bf(av.w);
  sT[cs+4][r]=f2bf(bq.x); sT[cs+5][r]=f2bf(bq.y); sT[cs+6][r]=f2bf(bq.z); sT[cs+7][r]=f2bf(bq.w);
  __syncthreads();
  int n = tid >> 2, kc = (tid & 3) << 3;
  *(short8v*)(Wt + (size_t)(n0+n)*K + k0 + kc) = *(const short8v*)(&sT[n][kc]);
}

// ------------------- V bf16 [b*S][256] -> Vt bf16 [(b*8+h)*32+d][S]
__global__ __launch_bounds__(256) void vtrans_kernel(const unsigned short* __restrict__ V,
    unsigned short* __restrict__ Vt){
  __shared__ unsigned short sT[32][136];
  int kt = blockIdx.x & 15, bh = blockIdx.x >> 4;
  int h = bh & 7, b = bh >> 3;
  int t0 = kt << 7;
  int tid = threadIdx.x;
  int key = tid >> 1, half = (tid & 1) << 4;
  const unsigned short* vp = V + (size_t)(b*SEQ + t0 + key)*DM + h*DKH + half;
  union {short8v v; unsigned short u[8];} ua, ub;
  ua.v = *(const short8v*)vp;
  ub.v = *(const short8v*)(vp+8);
  #pragma unroll
  for (int j=0;j<8;++j){ sT[half+j][key] = ua.u[j]; sT[half+8+j][key] = ub.u[j]; }
  __syncthreads();
  int d = tid >> 3, kc = (tid & 7) << 4;
  unsigned short* op = Vt + (size_t)(bh*DKH + d)*SEQ + t0 + kc;
  *(short8v*)op     = *(const short8v*)(&sT[d][kc]);
  *(short8v*)(op+8) = *(const short8v*)(&sT[d][kc+8]);
}

// ---------------------------------------------- bf16 MFMA GEMM, 128x64 tile
// flags: 1 = relu, 2 = bf16 output
__global__ __launch_bounds__(256) void gemm_bf16(const unsigned short* __restrict__ A,
    const unsigned short* __restrict__ Bt, const float* __restrict__ bias,
    const float* __restrict__ Res, void* __restrict__ Cout,
    int M, int N, int K, int flags, float outscale){
  __shared__ unsigned short sA[8192];
  __shared__ unsigned short sB[4096];
  int nbk = N >> 6;
  int bx = blockIdx.x % nbk, by = blockIdx.x / nbk;
  int m0 = by << 7, n0 = bx << 6;
  int tid = threadIdx.x, w = tid >> 6, lane = tid & 63;
  int m16 = lane & 15, quad = lane >> 4;
  int wr = w & 1, wc = w >> 1;
  floatx4 acc[4][2];
  #pragma unroll
  for (int i=0;i<4;++i){ acc[i][0]=(floatx4){0,0,0,0}; acc[i][1]=(floatx4){0,0,0,0}; }
  for (int k0=0; k0<K; k0+=64){
    __syncthreads();
    #pragma unroll
    for (int i=0;i<4;++i){
      int c = tid + i*256;
      int l = c & 63, kk = (c>>6)&1, mt = c>>7;
      int row = m0 + mt*16 + (l&15);
      int col = k0 + kk*32 + ((l>>4)<<3);
      *(short8v*)(sA + c*8) = *(const short8v*)(A + (size_t)row*K + col);
    }
    #pragma unroll
    for (int i=0;i<2;++i){
      int c = tid + i*256;
      int l = c & 63, kk = (c>>6)&1, nt = c>>7;
      int row = n0 + nt*16 + (l&15);
      int col = k0 + kk*32 + ((l>>4)<<3);
      *(short8v*)(sB + c*8) = *(const short8v*)(Bt + (size_t)row*K + col);
    }
    __syncthreads();
    #pragma unroll
    for (int kk=0;kk<2;++kk){
      bf16x8 bf0 = *(const bf16x8*)(sB + (((wc*2+0)*2+kk)*64 + lane)*8);
      bf16x8 bf1 = *(const bf16x8*)(sB + (((wc*2+1)*2+kk)*64 + lane)*8);
      #pragma unroll
      for (int mt=0;mt<4;++mt){
        bf16x8 af = *(const bf16x8*)(sA + (((wr*4+mt)*2+kk)*64 + lane)*8);
        acc[mt][0] = __builtin_amdgcn_mfma_f32_16x16x32_bf16(af, bf0, acc[mt][0], 0,0,0);
        acc[mt][1] = __builtin_amdgcn_mfma_f32_16x16x32_bf16(af, bf1, acc[mt][1], 0,0,0);
      }
    }
  }
  float b0 = bias ? bias[n0 + wc*32 + m16]      : 0.0f;
  float b1 = bias ? bias[n0 + wc*32 + 16 + m16] : 0.0f;
  #pragma unroll
  for (int mt=0;mt<4;++mt){
    #pragma unroll
    for (int r=0;r<4;++r){
      size_t row = (size_t)m0 + wr*64 + mt*16 + quad*4 + r;
      int col0 = n0 + wc*32 + m16, col1 = col0 + 16;
      float v0 = acc[mt][0][r] + b0, v1 = acc[mt][1][r] + b1;
      if (Res){ v0 += Res[row*N + col0]; v1 += Res[row*N + col1]; }
      if (flags & 1){ v0 = fmaxf(v0, 0.0f); v1 = fmaxf(v1, 0.0f); }
      v0 *= outscale; v1 *= outscale;
      if (flags & 2){
        unsigned short* C = (unsigned short*)Cout;
        C[row*N + col0] = f2bf(v0); C[row*N + col1] = f2bf(v1);
      } else {
        float* C = (float*)Cout;
        C[row*N + col0] = v0; C[row*N + col1] = v1;
      }
    }
  }
}

// --------------------------------------------- bf16 MFMA GEMM, 64x64 tile
// (2 blocks/CU at N=256 grids — occupancy fix for the small GEMMs)
__global__ __launch_bounds__(256) void gemm64(const unsigned short* __restrict__ A,
    const unsigned short* __restrict__ Bt, const float* __restrict__ bias,
    const float* __restrict__ Res, void* __restrict__ Cout,
    int M, int N, int K, int flags, float outscale){
  __shared__ unsigned short sA[4096];
  __shared__ unsigned short sB[4096];
  int nbk = N >> 6;
  int bx = blockIdx.x % nbk, by = blockIdx.x / nbk;
  int m0 = by << 6, n0 = bx << 6;
  int tid = threadIdx.x, w = tid >> 6, lane = tid & 63;
  int m16 = lane & 15, quad = lane >> 4;
  int wr = w & 1, wc = w >> 1;
  floatx4 acc[2][2];
  acc[0][0]=(floatx4){0,0,0,0}; acc[0][1]=(floatx4){0,0,0,0};
  acc[1][0]=(floatx4){0,0,0,0}; acc[1][1]=(floatx4){0,0,0,0};
  for (int k0=0; k0<K; k0+=64){
    __syncthreads();
    #pragma unroll
    for (int i=0;i<2;++i){
      int c = tid + i*256;
      int l = c & 63, kk = (c>>6)&1, mt = c>>7;
      int row = m0 + mt*16 + (l&15);
      int col = k0 + kk*32 + ((l>>4)<<3);
      *(short8v*)(sA + c*8) = *(const short8v*)(A + (size_t)row*K + col);
      int rowb = n0 + mt*16 + (l&15);
      *(short8v*)(sB + c*8) = *(const short8v*)(Bt + (size_t)rowb*K + col);
    }
    __syncthreads();
    #pragma unroll
    for (int kk=0;kk<2;++kk){
      bf16x8 bf0 = *(const bf16x8*)(sB + (((wc*2+0)*2+kk)*64 + lane)*8);
      bf16x8 bf1 = *(const bf16x8*)(sB + (((wc*2+1)*2+kk)*64 + lane)*8);
      bf16x8 af0 = *(const bf16x8*)(sA + (((wr*2+0)*2+kk)*64 + lane)*8);
      bf16x8 af1 = *(const bf16x8*)(sA + (((wr*2+1)*2+kk)*64 + lane)*8);
      acc[0][0] = __builtin_amdgcn_mfma_f32_16x16x32_bf16(af0, bf0, acc[0][0], 0,0,0);
      acc[0][1] = __builtin_amdgcn_mfma_f32_16x16x32_bf16(af0, bf1, acc[0][1], 0,0,0);
      acc[1][0] = __builtin_amdgcn_mfma_f32_16x16x32_bf16(af1, bf0, acc[1][0], 0,0,0);
      acc[1][1] = __builtin_amdgcn_mfma_f32_16x16x32_bf16(af1, bf1, acc[1][1], 0,0,0);
    }
  }
  float b0 = bias ? bias[n0 + wc*32 + m16]      : 0.0f;
  float b1 = bias ? bias[n0 + wc*32 + 16 + m16] : 0.0f;
  #pragma unroll
  for (int mt=0;mt<2;++mt){
    #pragma unroll
    for (int r=0;r<4;++r){
      size_t row = (size_t)m0 + (wr*2+mt)*16 + quad*4 + r;
      int col0 = n0 + wc*32 + m16, col1 = col0 + 16;
      float v0 = acc[mt][0][r] + b0, v1 = acc[mt][1][r] + b1;
      if (Res){ v0 += Res[row*N + col0]; v1 += Res[row*N + col1]; }
      if (flags & 1){ v0 = fmaxf(v0, 0.0f); v1 = fmaxf(v1, 0.0f); }
      v0 *= outscale; v1 *= outscale;
      if (flags & 2){
        unsigned short* C = (unsigned short*)Cout;
        C[row*N + col0] = f2bf(v0); C[row*N + col1] = f2bf(v1);
      } else {
        float* C = (float*)Cout;
        C[row*N + col0] = v0; C[row*N + col1] = v1;
      }
    }
  }
}

// ---------------------- fused QKV GEMM: A[8192x256] @ wqkv[768x256]^T
// seg 0 (cols 0-255) -> Q (scaled by QSCALE), 1 -> K, 2 -> V. bf16 out.
__global__ __launch_bounds__(256) void gemm_qkv(const unsigned short* __restrict__ A,
    const unsigned short* __restrict__ Bt,
    const float* __restrict__ bq, const float* __restrict__ bk, const float* __restrict__ bv,
    unsigned short* __restrict__ outq, unsigned short* __restrict__ outk,
    unsigned short* __restrict__ outv){
  __shared__ unsigned short sA[8192];
  __shared__ unsigned short sB[4096];
  int bx = blockIdx.x % 12, by = blockIdx.x / 12;
  int m0 = by << 7, n0 = bx << 6;
  int tid = threadIdx.x, w = tid >> 6, lane = tid & 63;
  int m16 = lane & 15, quad = lane >> 4;
  int wr = w & 1, wc = w >> 1;
  floatx4 acc[4][2];
  #pragma unroll
  for (int i=0;i<4;++i){ acc[i][0]=(floatx4){0,0,0,0}; acc[i][1]=(floatx4){0,0,0,0}; }
  for (int k0=0; k0<256; k0+=64){
    __syncthreads();
    #pragma unroll
    for (int i=0;i<4;++i){
      int c = tid + i*256;
      int l = c & 63, kk = (c>>6)&1, mt = c>>7;
      int row = m0 + mt*16 + (l&15);
      int col = k0 + kk*32 + ((l>>4)<<3);
      *(short8v*)(sA + c*8) = *(const short8v*)(A + (size_t)row*256 + col);
    }
    #pragma unroll
    for (int i=0;i<2;++i){
      int c = tid + i*256;
      int l = c & 63, kk = (c>>6)&1, nt = c>>7;
      int row = n0 + nt*16 + (l&15);
      int col = k0 + kk*32 + ((l>>4)<<3);
      *(short8v*)(sB + c*8) = *(const short8v*)(Bt + (size_t)row*256 + col);
    }
    __syncthreads();
    #pragma unroll
    for (int kk=0;kk<2;++kk){
      bf16x8 bf0 = *(const bf16x8*)(sB + (((wc*2+0)*2+kk)*64 + lane)*8);
      bf16x8 bf1 = *(const bf16x8*)(sB + (((wc*2+1)*2+kk)*64 + lane)*8);
      #pragma unroll
      for (int mt=0;mt<4;++mt){
        bf16x8 af = *(const bf16x8*)(sA + (((wr*4+mt)*2+kk)*64 + lane)*8);
        acc[mt][0] = __builtin_amdgcn_mfma_f32_16x16x32_bf16(af, bf0, acc[mt][0], 0,0,0);
        acc[mt][1] = __builtin_amdgcn_mfma_f32_16x16x32_bf16(af, bf1, acc[mt][1], 0,0,0);
      }
    }
  }
  int seg = n0 >> 8;
  int nb  = n0 & 255;
  unsigned short* C = (seg==0) ? outq : ((seg==1) ? outk : outv);
  const float* bias = (seg==0) ? bq : ((seg==1) ? bk : bv);
  float scale = (seg==0) ? QSCALE : 1.0f;
  float b0 = bias[nb + wc*32 + m16];
  float b1 = bias[nb + wc*32 + 16 + m16];
  #pragma unroll
  for (int mt=0;mt<4;++mt){
    #pragma unroll
    for (int r=0;r<4;++r){
      size_t row = (size_t)m0 + wr*64 + mt*16 + quad*4 + r;
      int col0 = nb + wc*32 + m16, col1 = col0 + 16;
      C[row*256 + col0] = f2bf((acc[mt][0][r] + b0)*scale);
      C[row*256 + col1] = f2bf((acc[mt][1][r] + b1)*scale);
    }
  }
}

// ------------------------------------------------ fused flash MFMA attention
// No online max (scores are log2-domain, bounded far below exp2 overflow):
// p = exp2(s), l accumulated per-lane, single end reduction, O normalized once.
// sP chunk index XOR-swizzled with writer quad -> 2-way (free) store conflicts.
__global__ __launch_bounds__(256) void flash_kernel(
    const unsigned short* __restrict__ Qb, const unsigned short* __restrict__ Kb,
    const unsigned short* __restrict__ Vt, unsigned short* __restrict__ Obf,
    float* __restrict__ Lout){
  __shared__ unsigned short sK[4096];
  __shared__ unsigned short sV[4096];
  __shared__ unsigned short sP[4*2048];
  int qb = blockIdx.x & 31, bh = blockIdx.x >> 5;
  int h = bh & 7, b = bh >> 3;
  int tid = threadIdx.x, w = tid >> 6, lane = tid & 63;
  int m16 = lane & 15, quad = lane >> 4;
  int qrow0 = qb*64 + w*16;
  bf16x8 qfrag = *(const bf16x8*)(Qb + (size_t)(b*SEQ + qrow0 + m16)*DM + h*DKH + quad*8);
  floatx4 o0 = {0,0,0,0}, o1 = {0,0,0,0};
  float ls[4] = {0.f,0.f,0.f,0.f};
  unsigned short* sPw = sP + w*2048;
  // write slots: k2 = (kt&1)*16 + m16 -> chunk = ((kt&1)*2 + (m16>>3)) ^ quad
  int cE = (((m16>>3)  ) ^ quad)*8 + (m16&7);   // kt even
  int cO = (((m16>>3)+2) ^ quad)*8 + (m16&7);   // kt odd

  for (int t0=0; t0<SEQ; t0+=128){
    __syncthreads();
    #pragma unroll
    for (int i=0;i<2;++i){
      int c = tid + i*256;
      int l = c & 63;
      {
        int kt = c >> 6;
        int key = t0 + kt*16 + (l&15);
        int dc = (l>>4)<<3;
        *(short8v*)(sK + c*8) = *(const short8v*)(Kb + (size_t)(b*SEQ+key)*DM + h*DKH + dc);
      }
      {
        int nt = (c>>6)&1, ks = c>>7;
        int d = nt*16 + (l&15);
        int ko = ks*32 + ((l>>4)<<3);
        *(short8v*)(sV + c*8) = *(const short8v*)(Vt + (size_t)(bh*DKH + d)*SEQ + t0 + ko);
      }
    }
    __syncthreads();
    floatx4 z = {0,0,0,0};
    floatx4 s[8];
    #pragma unroll
    for (int kt=0;kt<8;++kt){
      bf16x8 kf = *(const bf16x8*)(sK + (kt*64+lane)*8);
      s[kt] = __builtin_amdgcn_mfma_f32_16x16x32_bf16(qfrag, kf, z, 0,0,0);
    }
    #pragma unroll
    for (int r=0;r<4;++r){
      int rowbase = (quad*4+r)*32;
      float rs = 0.0f;
      #pragma unroll
      for (int kt=0;kt<8;++kt){
        float p = exp2f(s[kt][r]);
        rs += p;
        union { float f; unsigned u; } pu; pu.f = p;
        sPw[(kt>>1)*512 + rowbase + ((kt&1) ? cO : cE)] = (unsigned short)(pu.u >> 16);
      }
      ls[r] += rs;
    }
    #pragma unroll
    for (int ks=0;ks<4;++ks){
      // read A[m=q=m16][k2=quad*8+j]: chunk (quad ^ (m16>>2)), contiguous j
      bf16x8 pf  = *(const bf16x8*)(sPw + ks*512 + m16*32 + ((quad ^ (m16>>2))<<3));
      bf16x8 vf0 = *(const bf16x8*)(sV + ((ks*2+0)*64+lane)*8);
      bf16x8 vf1 = *(const bf16x8*)(sV + ((ks*2+1)*64+lane)*8);
      o0 = __builtin_amdgcn_mfma_f32_16x16x32_bf16(pf, vf0, o0, 0,0,0);
      o1 = __builtin_amdgcn_mfma_f32_16x16x32_bf16(pf, vf1, o1, 0,0,0);
    }
  }
  #pragma unroll
  for (int r=0;r<4;++r){
    float l = ls[r];
    l += __shfl_xor(l, 1, 64);
    l += __shfl_xor(l, 2, 64);
    l += __shfl_xor(l, 4, 64);
    l += __shfl_xor(l, 8, 64);
    float inv = 1.0f / l;
    int q = qrow0 + quad*4 + r;
    size_t base = (size_t)(b*SEQ + q)*DM + h*DKH;
    Obf[base + m16]      = f2bf(o0[r]*inv);
    Obf[base + 16 + m16] = f2bf(o1[r]*inv);
    if (m16 == 0) Lout[(size_t)bh*SEQ + q] = inv;
  }
}

// --------------------- column sums of softmax weights (recompute S via MFMA)
__global__ __launch_bounds__(256) void colsum_kernel(
    const unsigned short* __restrict__ Qb, const unsigned short* __restrict__ Kb,
    const float* __restrict__ Lv, float* __restrict__ col){
  __shared__ unsigned short sQ[2048];
  __shared__ float sL[64];
  int kc = blockIdx.x & 31, bh = blockIdx.x >> 5;
  int h = bh & 7, b = bh >> 3;
  int tid = threadIdx.x, w = tid >> 6, lane = tid & 63;
  int m16 = lane & 15, quad = lane >> 4;
  int key = kc*64 + w*16 + m16;
  bf16x8 kfrag = *(const bf16x8*)(Kb + (size_t)(b*SEQ+key)*DM + h*DKH + quad*8);
  float acc[4] = {0,0,0,0};
  for (int q0=0; q0<SEQ; q0+=64){
    __syncthreads();
    {
      int c = tid;
      int l = c & 63, qt = c >> 6;
      int q = q0 + qt*16 + (l&15);
      int dc = (l>>4)<<3;
      *(short8v*)(sQ + c*8) = *(const short8v*)(Qb + (size_t)(b*SEQ+q)*DM + h*DKH + dc);
      if (tid < 64) sL[tid] = Lv[(size_t)bh*SEQ + q0 + tid];
    }
    __syncthreads();
    floatx4 z = {0,0,0,0};
    #pragma unroll
    for (int qt=0;qt<4;++qt){
      bf16x8 qf = *(const bf16x8*)(sQ + (qt*64+lane)*8);
      floatx4 t = __builtin_amdgcn_mfma_f32_16x16x32_bf16(kfrag, qf, z, 0,0,0);
      float lq = sL[qt*16+m16];
      #pragma unroll
      for (int r=0;r<4;++r) acc[r] += exp2f(t[r])*lq;
    }
  }
  #pragma unroll
  for (int r=0;r<4;++r){
    float v = acc[r];
    v += __shfl_xor(v, 1, 64);
    v += __shfl_xor(v, 2, 64);
    v += __shfl_xor(v, 4, 64);
    v += __shfl_xor(v, 8, 64);
    if (m16 == 0) col[(size_t)bh*SEQ + kc*64 + w*16 + quad*4 + r] = v;
  }
}

// ------------------------------------- importance = 0.7*G + 0.3*L (fp64 acc)
__global__ __launch_bounds__(256) void imp_kernel(const float* __restrict__ colG,
    const float* __restrict__ colL, float* __restrict__ imp){
  int i = blockIdx.x*256 + threadIdx.x;
  int b = i >> 11, t = i & 2047;
  double sg = 0.0, sl = 0.0;
  for (int h=0; h<8; ++h){
    sg += (double)colG[(size_t)(b*8+h)*SEQ + t];
    sl += (double)colL[(size_t)(b*8+h)*SEQ + t];
  }
  imp[i] = (float)(0.7*sg + 0.3*sl);
}

// --------------------- rank of each element (desc value, asc index tie-break)
__global__ __launch_bounds__(256) void rank_kernel(const float* __restrict__ imp,
    int* __restrict__ rank){
  __shared__ float sv[2048];
  int b = blockIdx.x >> 3;
  int chunk = blockIdx.x & 7;
  for (int i=threadIdx.x; i<2048; i+=256) sv[i] = imp[b*2048 + i];
  __syncthreads();
  int i = chunk*256 + threadIdx.x;
  float v = sv[i];
  int r = 0;
  for (int j=0; j<2048; j+=4){
    float4 vj = *(const float4*)&sv[j];
    r += (vj.x > v) || (vj.x == v && (j+0) < i);
    r += (vj.y > v) || (vj.y == v && (j+1) < i);
    r += (vj.z > v) || (vj.z == v && (j+2) < i);
    r += (vj.w > v) || (vj.w == v && (j+3) < i);
  }
  rank[b*2048 + i] = r;
}

// --------------------- compact indices with rank < KK (ascending order)
__global__ __launch_bounds__(256) void compact_kernel(const int* __restrict__ rank,
    int KK, int* __restrict__ idxout){
  __shared__ int swave[4];
  int b = blockIdx.x;
  int tid = threadIdx.x, w = tid >> 6, lane = tid & 63;
  int base = tid*8;
  int f[8]; int c = 0;
  #pragma unroll
  for (int j=0;j<8;++j){ f[j] = (rank[b*2048 + base + j] < KK) ? 1 : 0; c += f[j]; }
  int pref = c;
  #pragma unroll
  for (int off=1; off<64; off<<=1){
    int t = __shfl_up(pref, off, 64);
    if (lane >= off) pref += t;
  }
  if (lane == 63) swave[w] = pref;
  __syncthreads();
  int wbase = 0;
  for (int k=0;k<w;++k) wbase += swave[k];
  int pos = wbase + pref - c;
  #pragma unroll
  for (int j=0;j<8;++j){
    if (f[j]) idxout[b*KK + pos++] = base + j;
  }
}

// --------------------------------------- gather + BatchNorm + write idx
__global__ __launch_bounds__(256) void final_kernel(const float* __restrict__ rb,
    const int* __restrict__ idx, const float* __restrict__ g, const float* __restrict__ bt,
    const float* __restrict__ mean, const float* __restrict__ var,
    float* __restrict__ out, int KK){
  int row = blockIdx.x*4 + (threadIdx.x>>6);
  int lane = threadIdx.x & 63;
  int total = NBATCH*KK;
  if (row < total){
    int b = row / KK;
    int src = idx[row];
    float4 v  = *(const float4*)(rb + ((size_t)(b*SEQ+src))*DM + lane*4);
    float4 gm = *(const float4*)(mean + lane*4);
    float4 gv = *(const float4*)(var  + lane*4);
    float4 gg = *(const float4*)(g    + lane*4);
    float4 gb = *(const float4*)(bt   + lane*4);
    float4 o;
    o.x = (v.x-gm.x)*rsqrtf(gv.x+1e-3f)*gg.x + gb.x;
    o.y = (v.y-gm.y)*rsqrtf(gv.y+1e-3f)*gg.y + gb.y;
    o.z = (v.z-gm.z)*rsqrtf(gv.z+1e-3f)*gg.z + gb.z;
    o.w = (v.w-gm.w)*rsqrtf(gv.w+1e-3f)*gg.w + gb.w;
    *(float4*)(out + (size_t)row*DM + lane*4) = o;
  }
  int gid = blockIdx.x*256 + threadIdx.x;
  if (gid < total) out[(size_t)total*DM + gid] = (float)idx[gid];
}

// ================================================================== launch
extern "C" void kernel_launch(void* const* d_in, const int* in_sizes, int n_in,
                              void* d_out, int out_size, void* d_ws, size_t ws_size,
                              hipStream_t stream){
  (void)in_sizes; (void)n_in; (void)ws_size;
  const float* x    = (const float*)d_in[0];
  const float* ln1g = (const float*)d_in[1];
  const float* ln1b = (const float*)d_in[2];
  const float* ln2g = (const float*)d_in[3];
  const float* ln2b = (const float*)d_in[4];
  const float* ln3g = (const float*)d_in[5];
  const float* ln3b = (const float*)d_in[6];
  const float* gqw = (const float*)d_in[7];  const float* gqb = (const float*)d_in[8];
  const float* gkw = (const float*)d_in[9];  const float* gkb = (const float*)d_in[10];
  const float* gvw = (const float*)d_in[11]; const float* gvb = (const float*)d_in[12];
  const float* gow = (const float*)d_in[13]; const float* gob = (const float*)d_in[14];
  const float* lqw = (const float*)d_in[15]; const float* lqb = (const float*)d_in[16];
  const float* lkw = (const float*)d_in[17]; const float* lkb = (const float*)d_in[18];
  const float* lvw = (const float*)d_in[19]; const float* lvb = (const float*)d_in[20];
  const float* low = (const float*)d_in[21]; const float* lob = (const float*)d_in[22];
  const float* fw1 = (const float*)d_in[23]; const float* fb1 = (const float*)d_in[24];
  const float* fw2 = (const float*)d_in[25]; const float* fb2 = (const float*)d_in[26];
  const float* resw = (const float*)d_in[27]; const float* resb = (const float*)d_in[28];
  const float* bng = (const float*)d_in[29]; const float* bnb = (const float*)d_in[30];
  const float* bnm = (const float*)d_in[31]; const float* bnv = (const float*)d_in[32];

  float* ws = (float*)d_ws;
  const size_t M1 = 2097152;                 // B*S*D
  float* r1 = ws;
  float* r2 = ws + M1;
  float* r3 = ws + 2*M1;
  unsigned short* nb  = (unsigned short*)(ws + 3*M1);
  unsigned short* qbf = (unsigned short*)(ws + 3*M1 + M1/2);
  unsigned short* kbf = (unsigned short*)(ws + 4*M1);
  unsigned short* vbf = (unsigned short*)(ws + 4*M1 + M1/2);
  unsigned short* vtb = (unsigned short*)(ws + 5*M1);
  unsigned short* obf = (unsigned short*)(ws + 5*M1 + M1/2);
  unsigned short* h1  = (unsigned short*)(ws + 6*M1);   // 8192x1024 bf16
  unsigned short* wT  = (unsigned short*)(ws + 8*M1);
  unsigned short* wgq = wT;            unsigned short* wgk = wT + 65536;
  unsigned short* wgv = wT + 131072;   unsigned short* wgo = wT + 196608;
  unsigned short* wlq = wT + 262144;   unsigned short* wlk = wT + 327680;
  unsigned short* wlv = wT + 393216;   unsigned short* wlo = wT + 458752;
  unsigned short* wre = wT + 524288;
  unsigned short* wf1 = wT + 589824;
  unsigned short* wf2 = wT + 851968;
  unsigned short* xbf = (unsigned short*)(ws + 9*M1);
  float* Ls   = ws + 10*M1;
  float* colG = ws + 10*M1 + 65536;
  float* colL = ws + 10*M1 + 131072;
  float* impb = ws + 10*M1 + 196608;
  int*   rnk  = (int*)(ws + 10*M1 + 204800);
  int*   idxb = (int*)(ws + 10*M1 + 212992);

  int KK = out_size / (NBATCH*(DM+1));
  float* out = (float*)d_out;

  // ---- weight prep: one batched launch (11 transposes)
  WtArgs wa;
  const float* srcs[11] = {gqw,gkw,gvw,gow,lqw,lkw,lvw,low,resw,fw1,fw2};
  unsigned short* dsts[11] = {wgq,wgk,wgv,wgo,wlq,wlk,wlv,wlo,wre,wf1,wf2};
  int Ks[11] = {256,256,256,256,256,256,256,256,256,256,1024};
  int Ns[11] = {256,256,256,256,256,256,256,256,256,1024,256};
  int acc = 0;
  for (int i=0;i<11;++i){
    wa.src[i]=srcs[i]; wa.dst[i]=dsts[i]; wa.K[i]=Ks[i]; wa.N[i]=Ns[i];
    wa.blk0[i]=acc; acc += (Ks[i]>>5)*(Ns[i]>>6);
  }
  wa.blk0[11]=acc;
  wtrans_all<<<acc,256,0,stream>>>(wa);
  cvt_kernel<<<2048,256,0,stream>>>(x, xbf, (int)(M1/4));

  // ---- block 1: global attention
  ln_kernel<<<2048,256,0,stream>>>(x, ln1g, ln1b, nb);
  gemm_qkv<<<768,256,0,stream>>>(nb, wgq, gqb, gkb, gvb, qbf, kbf, vbf);
  vtrans_kernel<<<512,256,0,stream>>>(vbf, vtb);
  flash_kernel<<<1024,256,0,stream>>>(qbf, kbf, vtb, obf, Ls);
  colsum_kernel<<<1024,256,0,stream>>>(qbf, kbf, Ls, colG);
  gemm64<<<512,256,0,stream>>>(obf, wgo, gob, x, r1, 8192,256,256, 0, 1.0f);

  // ---- block 2: local attention
  ln_kernel<<<2048,256,0,stream>>>(r1, ln2g, ln2b, nb);
  gemm_qkv<<<768,256,0,stream>>>(nb, wlq, lqb, lkb, lvb, qbf, kbf, vbf);
  vtrans_kernel<<<512,256,0,stream>>>(vbf, vtb);
  flash_kernel<<<1024,256,0,stream>>>(qbf, kbf, vtb, obf, Ls);
  colsum_kernel<<<1024,256,0,stream>>>(qbf, kbf, Ls, colL);
  gemm64<<<512,256,0,stream>>>(obf, wlo, lob, r1, r2, 8192,256,256, 0, 1.0f);

  // ---- FFN
  ln_kernel<<<2048,256,0,stream>>>(r2, ln3g, ln3b, nb);
  gemm_bf16<<<1024,256,0,stream>>>(nb, wf1, fb1, nullptr, h1, 8192,1024,256, 1|2, 1.0f);
  gemm64<<<512,256,0,stream>>>(h1, wf2, fb2, r2, r3, 8192,256,1024, 0, 1.0f);
  gemm64<<<512,256,0,stream>>>(xbf, wre, resb, r3, r3, 8192,256,256, 0, 1.0f);

  // ---- importance -> rank -> compact -> gather + BN + idx
  imp_kernel<<<32,256,0,stream>>>(colG, colL, impb);
  rank_kernel<<<32,256,0,stream>>>(impb, rnk);
  compact_kernel<<<NBATCH,256,0,stream>>>(rnk, KK, idxb);
  int total = NBATCH*KK;
  final_kernel<<<(total+3)/4,256,0,stream>>>(r3, idxb, bng, bnb, bnm, bnv, out, KK);
}

// Round 6
// 482.242 us; speedup vs baseline: 4.7139x; 1.0698x over previous
//
#include <hip/hip_runtime.h>

#define SEQ 2048
#define DM 256
#define NH 8
#define DKH 32
#define NBATCH 4
#define SCALE 0.17677669529663687f
#define QSCALE (0.17677669529663687f * 1.4426950408889634f)   // fold log2(e): p = exp2(s)

typedef __attribute__((ext_vector_type(8))) __bf16 bf16x8;
typedef __attribute__((ext_vector_type(4))) float floatx4;
typedef __attribute__((ext_vector_type(8))) short short8v;
typedef __attribute__((ext_vector_type(2))) unsigned int uint2v;

__device__ inline unsigned short f2bf(float x){
  union { float f; unsigned u; } v; v.f = x;
  unsigned r = v.u + 0x7FFFu + ((v.u >> 16) & 1u);
  return (unsigned short)(r >> 16);
}
__device__ inline unsigned pack2bf(float a, float b){  // trunc: low=a, high=b
  union { float f; unsigned u; } ua, ub; ua.f = a; ub.f = b;
  return (ua.u >> 16) | (ub.u & 0xFFFF0000u);
}

// ------------------------------------------- LayerNorm fp32 in -> bf16 out
__global__ __launch_bounds__(256) void ln_kernel(const float* __restrict__ X,
    const float* __restrict__ G, const float* __restrict__ Bv,
    unsigned short* __restrict__ Y){
  int row = blockIdx.x*4 + (threadIdx.x>>6);
  int lane = threadIdx.x & 63;
  const float4 v = *(const float4*)(X + (size_t)row*DM + lane*4);
  float s = v.x+v.y+v.z+v.w;
  #pragma unroll
  for (int off=32; off; off>>=1) s += __shfl_xor(s, off, 64);
  float mean = s * (1.0f/DM);
  float dx=v.x-mean, dy=v.y-mean, dz=v.z-mean, dw=v.w-mean;
  float ss = dx*dx+dy*dy+dz*dz+dw*dw;
  #pragma unroll
  for (int off=32; off; off>>=1) ss += __shfl_xor(ss, off, 64);
  float r = rsqrtf(ss*(1.0f/DM) + 1e-6f);
  const float4 g = *(const float4*)(G + lane*4);
  const float4 b = *(const float4*)(Bv + lane*4);
  ushort4 o;
  o.x = f2bf(dx*r*g.x + b.x);
  o.y = f2bf(dy*r*g.y + b.y);
  o.z = f2bf(dz*r*g.z + b.z);
  o.w = f2bf(dw*r*g.w + b.w);
  *(ushort4*)(Y + (size_t)row*DM + lane*4) = o;
}

// ----------------------------------------------- fp32 -> bf16 plain convert
__global__ __launch_bounds__(256) void cvt_kernel(const float* __restrict__ src,
    unsigned short* __restrict__ dst, int n4){
  int i = blockIdx.x*256 + threadIdx.x;
  if (i >= n4) return;
  float4 v = ((const float4*)src)[i];
  ushort4 o;
  o.x = f2bf(v.x); o.y = f2bf(v.y); o.z = f2bf(v.z); o.w = f2bf(v.w);
  ((ushort4*)dst)[i] = o;
}

// ------------- batched weight transpose+convert: fp32 [K][N] -> bf16 [N][K]
struct WtArgs {
  const float* src[11];
  unsigned short* dst[11];
  int K[11], N[11];
  int blk0[12];
};
__global__ __launch_bounds__(256) void wtrans_all(WtArgs a){
  __shared__ unsigned short sT[64][40];
  int wi = 0;
  while (blockIdx.x >= (unsigned)a.blk0[wi+1]) ++wi;
  int blk = blockIdx.x - a.blk0[wi];
  const float* W = a.src[wi];
  unsigned short* Wt = a.dst[wi];
  int K = a.K[wi], N = a.N[wi];
  int nbk = N >> 6;
  int bx = blk % nbk, by = blk / nbk;
  int k0 = by << 5, n0 = bx << 6;
  int tid = threadIdx.x;
  int r = tid >> 3, cs = (tid & 7) << 3;
  const float* ip = W + (size_t)(k0+r)*N + n0 + cs;
  float4 av = *(const float4*)ip;
  float4 bq = *(const float4*)(ip+4);
  sT[cs+0][r]=f2bf(av.x); sT[cs+1][r]=f2bf(av.y); sT[cs+2][r]=f2bf(av.z); sT[cs+3][r]=f2bf(av.w);
  sT[cs+4][r]=f2bf(bq.x); sT[cs+5][r]=f2bf(bq.y); sT[cs+6][r]=f2bf(bq.z); sT[cs+7][r]=f2bf(bq.w);
  __syncthreads();
  int n = tid >> 2, kc = (tid & 3) << 3;
  *(short8v*)(Wt + (size_t)(n0+n)*K + k0 + kc) = *(const short8v*)(&sT[n][kc]);
}

// ------------------- V bf16 [b*S][256] -> Vt bf16 [(b*8+h)*32+d][S]
__global__ __launch_bounds__(256) void vtrans_kernel(const unsigned short* __restrict__ V,
    unsigned short* __restrict__ Vt){
  __shared__ unsigned short sT[32][136];
  int kt = blockIdx.x & 15, bh = blockIdx.x >> 4;
  int h = bh & 7, b = bh >> 3;
  int t0 = kt << 7;
  int tid = threadIdx.x;
  int key = tid >> 1, half = (tid & 1) << 4;
  const unsigned short* vp = V + (size_t)(b*SEQ + t0 + key)*DM + h*DKH + half;
  union {short8v v; unsigned short u[8];} ua, ub;
  ua.v = *(const short8v*)vp;
  ub.v = *(const short8v*)(vp+8);
  #pragma unroll
  for (int j=0;j<8;++j){ sT[half+j][key] = ua.u[j]; sT[half+8+j][key] = ub.u[j]; }
  __syncthreads();
  int d = tid >> 3, kc = (tid & 7) << 4;
  unsigned short* op = Vt + (size_t)(bh*DKH + d)*SEQ + t0 + kc;
  *(short8v*)op     = *(const short8v*)(&sT[d][kc]);
  *(short8v*)(op+8) = *(const short8v*)(&sT[d][kc+8]);
}

// ---------------------------------------------- bf16 MFMA GEMM, 128x64 tile
// register-prefetched staging. flags: 1 = relu, 2 = bf16 output
__global__ __launch_bounds__(256) void gemm_bf16(const unsigned short* __restrict__ A,
    const unsigned short* __restrict__ Bt, const float* __restrict__ bias,
    const float* __restrict__ Res, void* __restrict__ Cout,
    int M, int N, int K, int flags, float outscale){
  __shared__ unsigned short sA[8192];
  __shared__ unsigned short sB[4096];
  int nbk = N >> 6;
  int bx = blockIdx.x % nbk, by = blockIdx.x / nbk;
  int m0 = by << 7, n0 = bx << 6;
  int tid = threadIdx.x, w = tid >> 6, lane = tid & 63;
  int m16 = lane & 15, quad = lane >> 4;
  int wr = w & 1, wc = w >> 1;
  const unsigned short* pa[4]; const unsigned short* pb[2];
  #pragma unroll
  for (int i=0;i<4;++i){
    int c = tid + i*256;
    int l = c & 63, kk = (c>>6)&1, mt = c>>7;
    pa[i] = A + (size_t)(m0 + mt*16 + (l&15))*K + kk*32 + ((l>>4)<<3);
  }
  #pragma unroll
  for (int i=0;i<2;++i){
    int c = tid + i*256;
    int l = c & 63, kk = (c>>6)&1, nt = c>>7;
    pb[i] = Bt + (size_t)(n0 + nt*16 + (l&15))*K + kk*32 + ((l>>4)<<3);
  }
  short8v ar[4], br[2];
  #pragma unroll
  for (int i=0;i<4;++i) ar[i] = *(const short8v*)pa[i];
  #pragma unroll
  for (int i=0;i<2;++i) br[i] = *(const short8v*)pb[i];
  floatx4 acc[4][2];
  #pragma unroll
  for (int i=0;i<4;++i){ acc[i][0]=(floatx4){0,0,0,0}; acc[i][1]=(floatx4){0,0,0,0}; }
  for (int k0=0; k0<K; k0+=64){
    __syncthreads();
    #pragma unroll
    for (int i=0;i<4;++i) *(short8v*)(sA + (tid+i*256)*8) = ar[i];
    #pragma unroll
    for (int i=0;i<2;++i) *(short8v*)(sB + (tid+i*256)*8) = br[i];
    __syncthreads();
    if (k0 + 64 < K){
      #pragma unroll
      for (int i=0;i<4;++i) ar[i] = *(const short8v*)(pa[i] + k0 + 64);
      #pragma unroll
      for (int i=0;i<2;++i) br[i] = *(const short8v*)(pb[i] + k0 + 64);
    }
    #pragma unroll
    for (int kk=0;kk<2;++kk){
      bf16x8 bf0 = *(const bf16x8*)(sB + (((wc*2+0)*2+kk)*64 + lane)*8);
      bf16x8 bf1 = *(const bf16x8*)(sB + (((wc*2+1)*2+kk)*64 + lane)*8);
      #pragma unroll
      for (int mt=0;mt<4;++mt){
        bf16x8 af = *(const bf16x8*)(sA + (((wr*4+mt)*2+kk)*64 + lane)*8);
        acc[mt][0] = __builtin_amdgcn_mfma_f32_16x16x32_bf16(af, bf0, acc[mt][0], 0,0,0);
        acc[mt][1] = __builtin_amdgcn_mfma_f32_16x16x32_bf16(af, bf1, acc[mt][1], 0,0,0);
      }
    }
  }
  float b0 = bias ? bias[n0 + wc*32 + m16]      : 0.0f;
  float b1 = bias ? bias[n0 + wc*32 + 16 + m16] : 0.0f;
  #pragma unroll
  for (int mt=0;mt<4;++mt){
    #pragma unroll
    for (int r=0;r<4;++r){
      size_t row = (size_t)m0 + wr*64 + mt*16 + quad*4 + r;
      int col0 = n0 + wc*32 + m16, col1 = col0 + 16;
      float v0 = acc[mt][0][r] + b0, v1 = acc[mt][1][r] + b1;
      if (Res){ v0 += Res[row*N + col0]; v1 += Res[row*N + col1]; }
      if (flags & 1){ v0 = fmaxf(v0, 0.0f); v1 = fmaxf(v1, 0.0f); }
      v0 *= outscale; v1 *= outscale;
      if (flags & 2){
        unsigned short* C = (unsigned short*)Cout;
        C[row*N + col0] = f2bf(v0); C[row*N + col1] = f2bf(v1);
      } else {
        float* C = (float*)Cout;
        C[row*N + col0] = v0; C[row*N + col1] = v1;
      }
    }
  }
}

// --------------------------------------------- bf16 MFMA GEMM, 64x64 tile
__global__ __launch_bounds__(256) void gemm64(const unsigned short* __restrict__ A,
    const unsigned short* __restrict__ Bt, const float* __restrict__ bias,
    const float* __restrict__ Res, void* __restrict__ Cout,
    int M, int N, int K, int flags, float outscale){
  __shared__ unsigned short sA[4096];
  __shared__ unsigned short sB[4096];
  int nbk = N >> 6;
  int bx = blockIdx.x % nbk, by = blockIdx.x / nbk;
  int m0 = by << 6, n0 = bx << 6;
  int tid = threadIdx.x, w = tid >> 6, lane = tid & 63;
  int m16 = lane & 15, quad = lane >> 4;
  int wr = w & 1, wc = w >> 1;
  const unsigned short* pa[2]; const unsigned short* pb[2];
  #pragma unroll
  for (int i=0;i<2;++i){
    int c = tid + i*256;
    int l = c & 63, kk = (c>>6)&1, mt = c>>7;
    int col = kk*32 + ((l>>4)<<3);
    pa[i] = A  + (size_t)(m0 + mt*16 + (l&15))*K + col;
    pb[i] = Bt + (size_t)(n0 + mt*16 + (l&15))*K + col;
  }
  short8v ar[2], br[2];
  #pragma unroll
  for (int i=0;i<2;++i){ ar[i] = *(const short8v*)pa[i]; br[i] = *(const short8v*)pb[i]; }
  floatx4 acc[2][2];
  acc[0][0]=(floatx4){0,0,0,0}; acc[0][1]=(floatx4){0,0,0,0};
  acc[1][0]=(floatx4){0,0,0,0}; acc[1][1]=(floatx4){0,0,0,0};
  for (int k0=0; k0<K; k0+=64){
    __syncthreads();
    #pragma unroll
    for (int i=0;i<2;++i){
      *(short8v*)(sA + (tid+i*256)*8) = ar[i];
      *(short8v*)(sB + (tid+i*256)*8) = br[i];
    }
    __syncthreads();
    if (k0 + 64 < K){
      #pragma unroll
      for (int i=0;i<2;++i){ ar[i] = *(const short8v*)(pa[i]+k0+64); br[i] = *(const short8v*)(pb[i]+k0+64); }
    }
    #pragma unroll
    for (int kk=0;kk<2;++kk){
      bf16x8 bf0 = *(const bf16x8*)(sB + (((wc*2+0)*2+kk)*64 + lane)*8);
      bf16x8 bf1 = *(const bf16x8*)(sB + (((wc*2+1)*2+kk)*64 + lane)*8);
      bf16x8 af0 = *(const bf16x8*)(sA + (((wr*2+0)*2+kk)*64 + lane)*8);
      bf16x8 af1 = *(const bf16x8*)(sA + (((wr*2+1)*2+kk)*64 + lane)*8);
      acc[0][0] = __builtin_amdgcn_mfma_f32_16x16x32_bf16(af0, bf0, acc[0][0], 0,0,0);
      acc[0][1] = __builtin_amdgcn_mfma_f32_16x16x32_bf16(af0, bf1, acc[0][1], 0,0,0);
      acc[1][0] = __builtin_amdgcn_mfma_f32_16x16x32_bf16(af1, bf0, acc[1][0], 0,0,0);
      acc[1][1] = __builtin_amdgcn_mfma_f32_16x16x32_bf16(af1, bf1, acc[1][1], 0,0,0);
    }
  }
  float b0 = bias ? bias[n0 + wc*32 + m16]      : 0.0f;
  float b1 = bias ? bias[n0 + wc*32 + 16 + m16] : 0.0f;
  #pragma unroll
  for (int mt=0;mt<2;++mt){
    #pragma unroll
    for (int r=0;r<4;++r){
      size_t row = (size_t)m0 + (wr*2+mt)*16 + quad*4 + r;
      int col0 = n0 + wc*32 + m16, col1 = col0 + 16;
      float v0 = acc[mt][0][r] + b0, v1 = acc[mt][1][r] + b1;
      if (Res){ v0 += Res[row*N + col0]; v1 += Res[row*N + col1]; }
      if (flags & 1){ v0 = fmaxf(v0, 0.0f); v1 = fmaxf(v1, 0.0f); }
      v0 *= outscale; v1 *= outscale;
      if (flags & 2){
        unsigned short* C = (unsigned short*)Cout;
        C[row*N + col0] = f2bf(v0); C[row*N + col1] = f2bf(v1);
      } else {
        float* C = (float*)Cout;
        C[row*N + col0] = v0; C[row*N + col1] = v1;
      }
    }
  }
}

// ---------------------- fused QKV GEMM: A[8192x256] @ wqkv[768x256]^T
__global__ __launch_bounds__(256) void gemm_qkv(const unsigned short* __restrict__ A,
    const unsigned short* __restrict__ Bt,
    const float* __restrict__ bq, const float* __restrict__ bk, const float* __restrict__ bv,
    unsigned short* __restrict__ outq, unsigned short* __restrict__ outk,
    unsigned short* __restrict__ outv){
  __shared__ unsigned short sA[8192];
  __shared__ unsigned short sB[4096];
  int bx = blockIdx.x % 12, by = blockIdx.x / 12;
  int m0 = by << 7, n0 = bx << 6;
  int tid = threadIdx.x, w = tid >> 6, lane = tid & 63;
  int m16 = lane & 15, quad = lane >> 4;
  int wr = w & 1, wc = w >> 1;
  const unsigned short* pa[4]; const unsigned short* pb[2];
  #pragma unroll
  for (int i=0;i<4;++i){
    int c = tid + i*256;
    int l = c & 63, kk = (c>>6)&1, mt = c>>7;
    pa[i] = A + (size_t)(m0 + mt*16 + (l&15))*256 + kk*32 + ((l>>4)<<3);
  }
  #pragma unroll
  for (int i=0;i<2;++i){
    int c = tid + i*256;
    int l = c & 63, kk = (c>>6)&1, nt = c>>7;
    pb[i] = Bt + (size_t)(n0 + nt*16 + (l&15))*256 + kk*32 + ((l>>4)<<3);
  }
  short8v ar[4], br[2];
  #pragma unroll
  for (int i=0;i<4;++i) ar[i] = *(const short8v*)pa[i];
  #pragma unroll
  for (int i=0;i<2;++i) br[i] = *(const short8v*)pb[i];
  floatx4 acc[4][2];
  #pragma unroll
  for (int i=0;i<4;++i){ acc[i][0]=(floatx4){0,0,0,0}; acc[i][1]=(floatx4){0,0,0,0}; }
  for (int k0=0; k0<256; k0+=64){
    __syncthreads();
    #pragma unroll
    for (int i=0;i<4;++i) *(short8v*)(sA + (tid+i*256)*8) = ar[i];
    #pragma unroll
    for (int i=0;i<2;++i) *(short8v*)(sB + (tid+i*256)*8) = br[i];
    __syncthreads();
    if (k0 + 64 < 256){
      #pragma unroll
      for (int i=0;i<4;++i) ar[i] = *(const short8v*)(pa[i] + k0 + 64);
      #pragma unroll
      for (int i=0;i<2;++i) br[i] = *(const short8v*)(pb[i] + k0 + 64);
    }
    #pragma unroll
    for (int kk=0;kk<2;++kk){
      bf16x8 bf0 = *(const bf16x8*)(sB + (((wc*2+0)*2+kk)*64 + lane)*8);
      bf16x8 bf1 = *(const bf16x8*)(sB + (((wc*2+1)*2+kk)*64 + lane)*8);
      #pragma unroll
      for (int mt=0;mt<4;++mt){
        bf16x8 af = *(const bf16x8*)(sA + (((wr*4+mt)*2+kk)*64 + lane)*8);
        acc[mt][0] = __builtin_amdgcn_mfma_f32_16x16x32_bf16(af, bf0, acc[mt][0], 0,0,0);
        acc[mt][1] = __builtin_amdgcn_mfma_f32_16x16x32_bf16(af, bf1, acc[mt][1], 0,0,0);
      }
    }
  }
  int seg = n0 >> 8;
  int nb  = n0 & 255;
  unsigned short* C = (seg==0) ? outq : ((seg==1) ? outk : outv);
  const float* bias = (seg==0) ? bq : ((seg==1) ? bk : bv);
  float scale = (seg==0) ? QSCALE : 1.0f;
  float b0 = bias[nb + wc*32 + m16];
  float b1 = bias[nb + wc*32 + 16 + m16];
  #pragma unroll
  for (int mt=0;mt<4;++mt){
    #pragma unroll
    for (int r=0;r<4;++r){
      size_t row = (size_t)m0 + wr*64 + mt*16 + quad*4 + r;
      int col0 = nb + wc*32 + m16, col1 = col0 + 16;
      C[row*256 + col0] = f2bf((acc[mt][0][r] + b0)*scale);
      C[row*256 + col1] = f2bf((acc[mt][1][r] + b1)*scale);
    }
  }
}

// ------------------------------------------------ flash v3: S^T formulation
// grid = 16 qblocks x 32 (b,h); 4 waves; wave = 32 q rows (2 Q frags).
// S^T = mfma(K_frag, Q_frag): lane holds 4 consecutive keys of one q row ->
// packed b64 P-stores into stride-136 rows (bank-floor), b128 A-frag reads
// (bank-floor), one scalar l per (lane,grp), 2-shuffle end reduction.
// K/V staged with register prefetch.
__global__ __launch_bounds__(256) void flash_kernel(
    const unsigned short* __restrict__ Qb, const unsigned short* __restrict__ Kb,
    const unsigned short* __restrict__ Vt, unsigned short* __restrict__ Obf,
    float* __restrict__ Lout){
  __shared__ unsigned short sK[4096];         // 8KB: (kt*64+lane)*8, key=kt*16+(l&15)
  __shared__ unsigned short sV[4096];         // 8KB: ((ks*2+nt)*64+lane)*8
  __shared__ unsigned short sP[4*32*136];     // 34816B: per-wave 32 q rows, stride 136
  int qb = blockIdx.x & 15, bh = blockIdx.x >> 4;
  int h = bh & 7, b = bh >> 3;
  int tid = threadIdx.x, w = tid >> 6, lane = tid & 63;
  int m16 = lane & 15, quad = lane >> 4;
  int qrow0 = qb*128 + w*32;
  const unsigned short* qp = Qb + (size_t)(b*SEQ + qrow0 + m16)*DM + h*DKH + quad*8;
  bf16x8 qf0 = *(const bf16x8*)qp;
  bf16x8 qf1 = *(const bf16x8*)(qp + 16*DM);
  floatx4 o00={0,0,0,0}, o01={0,0,0,0}, o10={0,0,0,0}, o11={0,0,0,0};
  float l0 = 0.f, l1 = 0.f;
  unsigned short* sPw = sP + w*(32*136);

  // staging pointers (per thread, 2 K-chunks + 2 V-chunks)
  const unsigned short* kp[2]; const unsigned short* vp[2];
  #pragma unroll
  for (int i=0;i<2;++i){
    int c = tid + i*256, l = c & 63;
    int kt = c >> 6;
    kp[i] = Kb + (size_t)(b*SEQ + kt*16 + (l&15))*DM + h*DKH + ((l>>4)<<3);
    int nt = (c>>6)&1, ks = c>>7;
    vp[i] = Vt + (size_t)(bh*DKH + nt*16 + (l&15))*SEQ + ks*32 + ((l>>4)<<3);
  }
  short8v kr[2], vr[2];
  #pragma unroll
  for (int i=0;i<2;++i){ kr[i] = *(const short8v*)kp[i]; vr[i] = *(const short8v*)vp[i]; }

  for (int t0=0; t0<SEQ; t0+=128){
    __syncthreads();
    #pragma unroll
    for (int i=0;i<2;++i){
      *(short8v*)(sK + (tid+i*256)*8) = kr[i];
      *(short8v*)(sV + (tid+i*256)*8) = vr[i];
    }
    __syncthreads();
    if (t0 + 128 < SEQ){
      #pragma unroll
      for (int i=0;i<2;++i){
        kr[i] = *(const short8v*)(kp[i] + (size_t)(t0+128)*DM);
        vr[i] = *(const short8v*)(vp[i] + (t0+128));
      }
    }
    // S^T + exp + packed P store
    #pragma unroll
    for (int kt=0;kt<8;++kt){
      bf16x8 kf = *(const bf16x8*)(sK + (kt*64+lane)*8);
      floatx4 z = {0,0,0,0};
      floatx4 s0 = __builtin_amdgcn_mfma_f32_16x16x32_bf16(kf, qf0, z, 0,0,0);
      floatx4 s1 = __builtin_amdgcn_mfma_f32_16x16x32_bf16(kf, qf1, z, 0,0,0);
      float p0 = exp2f(s0[0]), p1 = exp2f(s0[1]), p2 = exp2f(s0[2]), p3 = exp2f(s0[3]);
      l0 += (p0+p1)+(p2+p3);
      uint2v pk0; pk0.x = pack2bf(p0,p1); pk0.y = pack2bf(p2,p3);
      *(uint2v*)(sPw + m16*136 + kt*16 + quad*4) = pk0;
      float q0e = exp2f(s1[0]), q1e = exp2f(s1[1]), q2e = exp2f(s1[2]), q3e = exp2f(s1[3]);
      l1 += (q0e+q1e)+(q2e+q3e);
      uint2v pk1; pk1.x = pack2bf(q0e,q1e); pk1.y = pack2bf(q2e,q3e);
      *(uint2v*)(sPw + (16+m16)*136 + kt*16 + quad*4) = pk1;
    }
    // PV
    #pragma unroll
    for (int ks=0;ks<4;++ks){
      bf16x8 vf0 = *(const bf16x8*)(sV + ((ks*2+0)*64+lane)*8);
      bf16x8 vf1 = *(const bf16x8*)(sV + ((ks*2+1)*64+lane)*8);
      bf16x8 pf0 = *(const bf16x8*)(sPw + m16*136 + ks*32 + quad*8);
      bf16x8 pf1 = *(const bf16x8*)(sPw + (16+m16)*136 + ks*32 + quad*8);
      o00 = __builtin_amdgcn_mfma_f32_16x16x32_bf16(pf0, vf0, o00, 0,0,0);
      o01 = __builtin_amdgcn_mfma_f32_16x16x32_bf16(pf0, vf1, o01, 0,0,0);
      o10 = __builtin_amdgcn_mfma_f32_16x16x32_bf16(pf1, vf0, o10, 0,0,0);
      o11 = __builtin_amdgcn_mfma_f32_16x16x32_bf16(pf1, vf1, o11, 0,0,0);
    }
  }
  // l lives per-lane for q = qrow0 + (grp*16) + m16; reduce over quad lanes
  l0 += __shfl_xor(l0, 16, 64); l0 += __shfl_xor(l0, 32, 64);
  l1 += __shfl_xor(l1, 16, 64); l1 += __shfl_xor(l1, 32, 64);
  float inv0 = 1.0f / l0, inv1 = 1.0f / l1;
  #pragma unroll
  for (int r=0;r<4;++r){
    float iv0 = __shfl(inv0, quad*4 + r, 64);   // q = qrow0 + quad*4 + r
    float iv1 = __shfl(inv1, quad*4 + r, 64);
    int q0 = qrow0 + quad*4 + r;
    int q1 = q0 + 16;
    size_t base0 = (size_t)(b*SEQ + q0)*DM + h*DKH;
    size_t base1 = (size_t)(b*SEQ + q1)*DM + h*DKH;
    Obf[base0 + m16]      = f2bf(o00[r]*iv0);
    Obf[base0 + 16 + m16] = f2bf(o01[r]*iv0);
    Obf[base1 + m16]      = f2bf(o10[r]*iv1);
    Obf[base1 + 16 + m16] = f2bf(o11[r]*iv1);
    if (m16 == 0){
      Lout[(size_t)bh*SEQ + q0] = iv0;
      Lout[(size_t)bh*SEQ + q1] = iv1;
    }
  }
}

// --------------------- colsum v2: wave = 32 keys (2 K frags), block = 128 keys
__global__ __launch_bounds__(256) void colsum_kernel(
    const unsigned short* __restrict__ Qb, const unsigned short* __restrict__ Kb,
    const float* __restrict__ Lv, float* __restrict__ col){
  __shared__ unsigned short sQ[2048];
  __shared__ float sL[64];
  int kc = blockIdx.x & 15, bh = blockIdx.x >> 4;
  int h = bh & 7, b = bh >> 3;
  int tid = threadIdx.x, w = tid >> 6, lane = tid & 63;
  int m16 = lane & 15, quad = lane >> 4;
  int key0 = kc*128 + w*32;
  const unsigned short* kp = Kb + (size_t)(b*SEQ + key0 + m16)*DM + h*DKH + quad*8;
  bf16x8 kf0 = *(const bf16x8*)kp;
  bf16x8 kf1 = *(const bf16x8*)(kp + 16*DM);
  float acc0[4] = {0,0,0,0}, acc1[4] = {0,0,0,0};
  // staging: thread loads 1 Q chunk per iter
  int l = tid & 63, qt = tid >> 6;
  const unsigned short* qp = Qb + (size_t)(b*SEQ + qt*16 + (l&15))*DM + h*DKH + ((l>>4)<<3);
  short8v qr = *(const short8v*)qp;
  float lr = (tid < 64) ? Lv[(size_t)bh*SEQ + tid] : 0.0f;
  for (int q0=0; q0<SEQ; q0+=64){
    __syncthreads();
    *(short8v*)(sQ + tid*8) = qr;
    if (tid < 64) sL[tid] = lr;
    __syncthreads();
    if (q0 + 64 < SEQ){
      qr = *(const short8v*)(qp + (size_t)(q0+64)*DM);
      if (tid < 64) lr = Lv[(size_t)bh*SEQ + q0 + 64 + tid];
    }
    floatx4 z = {0,0,0,0};
    #pragma unroll
    for (int qt2=0;qt2<4;++qt2){
      bf16x8 qf = *(const bf16x8*)(sQ + (qt2*64+lane)*8);
      floatx4 t0 = __builtin_amdgcn_mfma_f32_16x16x32_bf16(kf0, qf, z, 0,0,0);
      floatx4 t1 = __builtin_amdgcn_mfma_f32_16x16x32_bf16(kf1, qf, z, 0,0,0);
      float lq = sL[qt2*16+m16];
      #pragma unroll
      for (int r=0;r<4;++r){ acc0[r] += exp2f(t0[r])*lq; acc1[r] += exp2f(t1[r])*lq; }
    }
  }
  #pragma unroll
  for (int r=0;r<4;++r){
    float v0 = acc0[r], v1 = acc1[r];
    v0 += __shfl_xor(v0, 1, 64); v0 += __shfl_xor(v0, 2, 64);
    v0 += __shfl_xor(v0, 4, 64); v0 += __shfl_xor(v0, 8, 64);
    v1 += __shfl_xor(v1, 1, 64); v1 += __shfl_xor(v1, 2, 64);
    v1 += __shfl_xor(v1, 4, 64); v1 += __shfl_xor(v1, 8, 64);
    if (m16 == 0){
      col[(size_t)bh*SEQ + key0 + quad*4 + r]      = v0;
      col[(size_t)bh*SEQ + key0 + 16 + quad*4 + r] = v1;
    }
  }
}

// ------------------------------------- importance = 0.7*G + 0.3*L (fp64 acc)
__global__ __launch_bounds__(256) void imp_kernel(const float* __restrict__ colG,
    const float* __restrict__ colL, float* __restrict__ imp){
  int i = blockIdx.x*256 + threadIdx.x;
  int b = i >> 11, t = i & 2047;
  double sg = 0.0, sl = 0.0;
  for (int h=0; h<8; ++h){
    sg += (double)colG[(size_t)(b*8+h)*SEQ + t];
    sl += (double)colL[(size_t)(b*8+h)*SEQ + t];
  }
  imp[i] = (float)(0.7*sg + 0.3*sl);
}

// --------------------- rank of each element (desc value, asc index tie-break)
__global__ __launch_bounds__(256) void rank_kernel(const float* __restrict__ imp,
    int* __restrict__ rank){
  __shared__ float sv[2048];
  int b = blockIdx.x >> 3;
  int chunk = blockIdx.x & 7;
  for (int i=threadIdx.x; i<2048; i+=256) sv[i] = imp[b*2048 + i];
  __syncthreads();
  int i = chunk*256 + threadIdx.x;
  float v = sv[i];
  int r = 0;
  for (int j=0; j<2048; j+=4){
    float4 vj = *(const float4*)&sv[j];
    r += (vj.x > v) || (vj.x == v && (j+0) < i);
    r += (vj.y > v) || (vj.y == v && (j+1) < i);
    r += (vj.z > v) || (vj.z == v && (j+2) < i);
    r += (vj.w > v) || (vj.w == v && (j+3) < i);
  }
  rank[b*2048 + i] = r;
}

// --------------------- compact indices with rank < KK (ascending order)
__global__ __launch_bounds__(256) void compact_kernel(const int* __restrict__ rank,
    int KK, int* __restrict__ idxout){
  __shared__ int swave[4];
  int b = blockIdx.x;
  int tid = threadIdx.x, w = tid >> 6, lane = tid & 63;
  int base = tid*8;
  int f[8]; int c = 0;
  #pragma unroll
  for (int j=0;j<8;++j){ f[j] = (rank[b*2048 + base + j] < KK) ? 1 : 0; c += f[j]; }
  int pref = c;
  #pragma unroll
  for (int off=1; off<64; off<<=1){
    int t = __shfl_up(pref, off, 64);
    if (lane >= off) pref += t;
  }
  if (lane == 63) swave[w] = pref;
  __syncthreads();
  int wbase = 0;
  for (int k=0;k<w;++k) wbase += swave[k];
  int pos = wbase + pref - c;
  #pragma unroll
  for (int j=0;j<8;++j){
    if (f[j]) idxout[b*KK + pos++] = base + j;
  }
}

// --------------------------------------- gather + BatchNorm + write idx
__global__ __launch_bounds__(256) void final_kernel(const float* __restrict__ rb,
    const int* __restrict__ idx, const float* __restrict__ g, const float* __restrict__ bt,
    const float* __restrict__ mean, const float* __restrict__ var,
    float* __restrict__ out, int KK){
  int row = blockIdx.x*4 + (threadIdx.x>>6);
  int lane = threadIdx.x & 63;
  int total = NBATCH*KK;
  if (row < total){
    int b = row / KK;
    int src = idx[row];
    float4 v  = *(const float4*)(rb + ((size_t)(b*SEQ+src))*DM + lane*4);
    float4 gm = *(const float4*)(mean + lane*4);
    float4 gv = *(const float4*)(var  + lane*4);
    float4 gg = *(const float4*)(g    + lane*4);
    float4 gb = *(const float4*)(bt   + lane*4);
    float4 o;
    o.x = (v.x-gm.x)*rsqrtf(gv.x+1e-3f)*gg.x + gb.x;
    o.y = (v.y-gm.y)*rsqrtf(gv.y+1e-3f)*gg.y + gb.y;
    o.z = (v.z-gm.z)*rsqrtf(gv.z+1e-3f)*gg.z + gb.z;
    o.w = (v.w-gm.w)*rsqrtf(gv.w+1e-3f)*gg.w + gb.w;
    *(float4*)(out + (size_t)row*DM + lane*4) = o;
  }
  int gid = blockIdx.x*256 + threadIdx.x;
  if (gid < total) out[(size_t)total*DM + gid] = (float)idx[gid];
}

// ================================================================== launch
extern "C" void kernel_launch(void* const* d_in, const int* in_sizes, int n_in,
                              void* d_out, int out_size, void* d_ws, size_t ws_size,
                              hipStream_t stream){
  (void)in_sizes; (void)n_in; (void)ws_size;
  const float* x    = (const float*)d_in[0];
  const float* ln1g = (const float*)d_in[1];
  const float* ln1b = (const float*)d_in[2];
  const float* ln2g = (const float*)d_in[3];
  const float* ln2b = (const float*)d_in[4];
  const float* ln3g = (const float*)d_in[5];
  const float* ln3b = (const float*)d_in[6];
  const float* gqw = (const float*)d_in[7];  const float* gqb = (const float*)d_in[8];
  const float* gkw = (const float*)d_in[9];  const float* gkb = (const float*)d_in[10];
  const float* gvw = (const float*)d_in[11]; const float* gvb = (const float*)d_in[12];
  const float* gow = (const float*)d_in[13]; const float* gob = (const float*)d_in[14];
  const float* lqw = (const float*)d_in[15]; const float* lqb = (const float*)d_in[16];
  const float* lkw = (const float*)d_in[17]; const float* lkb = (const float*)d_in[18];
  const float* lvw = (const float*)d_in[19]; const float* lvb = (const float*)d_in[20];
  const float* low = (const float*)d_in[21]; const float* lob = (const float*)d_in[22];
  const float* fw1 = (const float*)d_in[23]; const float* fb1 = (const float*)d_in[24];
  const float* fw2 = (const float*)d_in[25]; const float* fb2 = (const float*)d_in[26];
  const float* resw = (const float*)d_in[27]; const float* resb = (const float*)d_in[28];
  const float* bng = (const float*)d_in[29]; const float* bnb = (const float*)d_in[30];
  const float* bnm = (const float*)d_in[31]; const float* bnv = (const float*)d_in[32];

  float* ws = (float*)d_ws;
  const size_t M1 = 2097152;                 // B*S*D
  float* r1 = ws;
  float* r2 = ws + M1;
  float* r3 = ws + 2*M1;
  unsigned short* nb  = (unsigned short*)(ws + 3*M1);
  unsigned short* qbf = (unsigned short*)(ws + 3*M1 + M1/2);
  unsigned short* kbf = (unsigned short*)(ws + 4*M1);
  unsigned short* vbf = (unsigned short*)(ws + 4*M1 + M1/2);
  unsigned short* vtb = (unsigned short*)(ws + 5*M1);
  unsigned short* obf = (unsigned short*)(ws + 5*M1 + M1/2);
  unsigned short* h1  = (unsigned short*)(ws + 6*M1);   // 8192x1024 bf16
  unsigned short* wT  = (unsigned short*)(ws + 8*M1);
  unsigned short* wgq = wT;            unsigned short* wgk = wT + 65536;
  unsigned short* wgv = wT + 131072;   unsigned short* wgo = wT + 196608;
  unsigned short* wlq = wT + 262144;   unsigned short* wlk = wT + 327680;
  unsigned short* wlv = wT + 393216;   unsigned short* wlo = wT + 458752;
  unsigned short* wre = wT + 524288;
  unsigned short* wf1 = wT + 589824;
  unsigned short* wf2 = wT + 851968;
  unsigned short* xbf = (unsigned short*)(ws + 9*M1);
  float* Ls   = ws + 10*M1;
  float* colG = ws + 10*M1 + 65536;
  float* colL = ws + 10*M1 + 131072;
  float* impb = ws + 10*M1 + 196608;
  int*   rnk  = (int*)(ws + 10*M1 + 204800);
  int*   idxb = (int*)(ws + 10*M1 + 212992);

  int KK = out_size / (NBATCH*(DM+1));
  float* out = (float*)d_out;

  // ---- weight prep: one batched launch (11 transposes)
  WtArgs wa;
  const float* srcs[11] = {gqw,gkw,gvw,gow,lqw,lkw,lvw,low,resw,fw1,fw2};
  unsigned short* dsts[11] = {wgq,wgk,wgv,wgo,wlq,wlk,wlv,wlo,wre,wf1,wf2};
  int Ks[11] = {256,256,256,256,256,256,256,256,256,256,1024};
  int Ns[11] = {256,256,256,256,256,256,256,256,256,1024,256};
  int acc = 0;
  for (int i=0;i<11;++i){
    wa.src[i]=srcs[i]; wa.dst[i]=dsts[i]; wa.K[i]=Ks[i]; wa.N[i]=Ns[i];
    wa.blk0[i]=acc; acc += (Ks[i]>>5)*(Ns[i]>>6);
  }
  wa.blk0[11]=acc;
  wtrans_all<<<acc,256,0,stream>>>(wa);
  cvt_kernel<<<2048,256,0,stream>>>(x, xbf, (int)(M1/4));

  // ---- block 1: global attention
  ln_kernel<<<2048,256,0,stream>>>(x, ln1g, ln1b, nb);
  gemm_qkv<<<768,256,0,stream>>>(nb, wgq, gqb, gkb, gvb, qbf, kbf, vbf);
  vtrans_kernel<<<512,256,0,stream>>>(vbf, vtb);
  flash_kernel<<<512,256,0,stream>>>(qbf, kbf, vtb, obf, Ls);
  colsum_kernel<<<512,256,0,stream>>>(qbf, kbf, Ls, colG);
  gemm64<<<512,256,0,stream>>>(obf, wgo, gob, x, r1, 8192,256,256, 0, 1.0f);

  // ---- block 2: local attention
  ln_kernel<<<2048,256,0,stream>>>(r1, ln2g, ln2b, nb);
  gemm_qkv<<<768,256,0,stream>>>(nb, wlq, lqb, lkb, lvb, qbf, kbf, vbf);
  vtrans_kernel<<<512,256,0,stream>>>(vbf, vtb);
  flash_kernel<<<512,256,0,stream>>>(qbf, kbf, vtb, obf, Ls);
  colsum_kernel<<<512,256,0,stream>>>(qbf, kbf, Ls, colL);
  gemm64<<<512,256,0,stream>>>(obf, wlo, lob, r1, r2, 8192,256,256, 0, 1.0f);

  // ---- FFN
  ln_kernel<<<2048,256,0,stream>>>(r2, ln3g, ln3b, nb);
  gemm_bf16<<<1024,256,0,stream>>>(nb, wf1, fb1, nullptr, h1, 8192,1024,256, 1|2, 1.0f);
  gemm64<<<512,256,0,stream>>>(h1, wf2, fb2, r2, r3, 8192,256,1024, 0, 1.0f);
  gemm64<<<512,256,0,stream>>>(xbf, wre, resb, r3, r3, 8192,256,256, 0, 1.0f);

  // ---- importance -> rank -> compact -> gather + BN + idx
  imp_kernel<<<32,256,0,stream>>>(colG, colL, impb);
  rank_kernel<<<32,256,0,stream>>>(impb, rnk);
  compact_kernel<<<NBATCH,256,0,stream>>>(rnk, KK, idxb);
  int total = NBATCH*KK;
  final_kernel<<<(total+3)/4,256,0,stream>>>(r3, idxb, bng, bnb, bnm, bnv, out, KK);
}